// Round 1
// baseline (2055.374 us; speedup 1.0000x reference)
//
#include <hip/hip_runtime.h>
#include <math.h>

#define NN 25000
#define KNB 16
#define HH 128
#define VV 32000
#define BB 50
#define LL 128
#define NTK 4
#define NGRAPH 25

__device__ __forceinline__ float sigm(float x) { return 1.f / (1.f + expf(-x)); }

// ---------------- transpose 6 LSTM weight matrices (512,128)->(128,512) ----------------
__global__ __launch_bounds__(256) void transpose6_k(
    const float* __restrict__ s0, const float* __restrict__ s1,
    const float* __restrict__ s2, const float* __restrict__ s3,
    const float* __restrict__ s4, const float* __restrict__ s5,
    float* __restrict__ dst)
{
    int t = blockIdx.x * 256 + threadIdx.x;
    if (t >= 6 * 65536) return;
    int mat = t >> 16, r = t & 65535;
    int k = r >> 9, g = r & 511;
    const float* s = mat == 0 ? s0 : mat == 1 ? s1 : mat == 2 ? s2 : mat == 3 ? s3 : mat == 4 ? s4 : s5;
    dst[t] = s[g * 128 + k];
}

__global__ __launch_bounds__(256) void zero_k(float* __restrict__ p, int n)
{
    int i = blockIdx.x * 256 + threadIdx.x;
    if (i < n) p[i] = 0.f;
}

__global__ __launch_bounds__(256) void tokrev_k(const int* __restrict__ idx,
                                                const int* __restrict__ lens,
                                                int* __restrict__ tokrev)
{
    int t = blockIdx.x * 256 + threadIdx.x;
    if (t >= BB * LL) return;
    int b = t / LL, tt = t % LL;
    int r = lens[b] - 1 - tt;
    r = r < 0 ? 0 : (r > LL - 1 ? LL - 1 : r);
    tokrev[t] = idx[b * LL + r];
}

// ---------------- generic f32 GEMM: C[m,n] = ep(sum_k A[m,k]*W[k,n] + bias[n]) ----------------
// AMODE 0: A[m*lda+k]; 1: embed[gidx[m*gs+go]*128+k]; 2: k<128 embed-part else H2[m*128+(k-128)]
// EP 0: none; 1: relu; 2: sigmoid(v)*aux[m*ldaux+n]
template<int AMODE, int EP>
__global__ __launch_bounds__(256) void sgemm_k(
    const float* __restrict__ A, int lda,
    const int* __restrict__ gidx, int gstride, int goff,
    const float* __restrict__ H2,
    const float* __restrict__ W, int ldw,
    const float* __restrict__ bias,
    const float* __restrict__ aux, int ldaux,
    float* __restrict__ out, int ldo, int ocol,
    int M, int N, int K)
{
    __shared__ __align__(16) float As[16 * 132];
    __shared__ __align__(16) float Bs[16 * 136];
    const int tid = threadIdx.x;
    const int bm0 = blockIdx.x * 128;
    const int bn0 = blockIdx.y * 128;
    const int tx = tid & 15, ty = tid >> 4;
    float acc[8][8];
#pragma unroll
    for (int i = 0; i < 8; ++i)
#pragma unroll
        for (int j = 0; j < 8; ++j) acc[i][j] = 0.f;

    for (int kt = 0; kt < K; kt += 16) {
#pragma unroll
        for (int rep = 0; rep < 2; ++rep) {
            int id = tid + rep * 256;
            int row = id >> 2, kq = id & 3;
            int m = bm0 + row, k = kt + kq * 4;
            float4 av = make_float4(0.f, 0.f, 0.f, 0.f);
            if (m < M) {
                const float* src;
                if (AMODE == 0) {
                    src = A + (size_t)m * lda + k;
                } else if (AMODE == 1) {
                    int g = gidx[m * gstride + goff];
                    src = A + (size_t)g * 128 + k;
                } else {
                    if (k < 128) {
                        int g = gidx[m * gstride + goff];
                        src = A + (size_t)g * 128 + k;
                    } else {
                        src = H2 + (size_t)m * 128 + (k - 128);
                    }
                }
                av = *(const float4*)src;
            }
            As[(kq * 4 + 0) * 132 + row] = av.x;
            As[(kq * 4 + 1) * 132 + row] = av.y;
            As[(kq * 4 + 2) * 132 + row] = av.z;
            As[(kq * 4 + 3) * 132 + row] = av.w;
        }
#pragma unroll
        for (int rep = 0; rep < 2; ++rep) {
            int id = tid + rep * 256;
            int kr = id >> 5, n4 = id & 31;
            float4 bv = *(const float4*)(W + (size_t)(kt + kr) * ldw + bn0 + n4 * 4);
            *(float4*)&Bs[kr * 136 + n4 * 4] = bv;
        }
        __syncthreads();
#pragma unroll
        for (int k = 0; k < 16; ++k) {
            float4 aA = *(const float4*)&As[k * 132 + ty * 8];
            float4 aB = *(const float4*)&As[k * 132 + ty * 8 + 4];
            float4 bA = *(const float4*)&Bs[k * 136 + tx * 8];
            float4 bB = *(const float4*)&Bs[k * 136 + tx * 8 + 4];
            float a[8] = {aA.x, aA.y, aA.z, aA.w, aB.x, aB.y, aB.z, aB.w};
            float b[8] = {bA.x, bA.y, bA.z, bA.w, bB.x, bB.y, bB.z, bB.w};
#pragma unroll
            for (int i = 0; i < 8; ++i)
#pragma unroll
                for (int j = 0; j < 8; ++j) acc[i][j] += a[i] * b[j];
        }
        __syncthreads();
    }
#pragma unroll
    for (int i = 0; i < 8; ++i) {
        int m = bm0 + ty * 8 + i;
        if (m < M) {
#pragma unroll
            for (int j = 0; j < 8; ++j) {
                int n = bn0 + tx * 8 + j;
                float v = acc[i][j] + bias[n];
                if (EP == 1) v = fmaxf(v, 0.f);
                if (EP == 2) v = sigm(v) * aux[(size_t)m * ldaux + n];
                out[(size_t)m * ldo + ocol + n] = v;
            }
        }
    }
}

// ---------------- node LSTM cell elementwise ----------------
__global__ __launch_bounds__(256) void lstm_cell_k(const float* __restrict__ G,
                                                   float* __restrict__ h,
                                                   float* __restrict__ c, int M)
{
    int i = blockIdx.x * 256 + threadIdx.x;
    if (i >= M * HH) return;
    int m = i >> 7, j = i & 127;
    const float* g = G + (size_t)m * 512;
    float i_ = g[j], f_ = g[128 + j], gg = g[256 + j], o_ = g[384 + j];
    float cc = c[i];
    cc = sigm(f_) * cc + sigm(i_) * tanhf(gg);
    float hh = sigm(o_) * tanhf(cc);
    c[i] = cc;
    h[i] = hh;
}

// ---------------- per-sequence LSTM recurrence (block = dir*50+b) ----------------
__global__ __launch_bounds__(512) void seq_lstm_k(const float* __restrict__ xgf,
                                                  const float* __restrict__ xgb,
                                                  const float* __restrict__ wt_all,
                                                  const int* __restrict__ lens,
                                                  float* __restrict__ senc)
{
    int bid = blockIdx.x;
    int dir = bid >= BB ? 1 : 0;
    int b = dir ? bid - BB : bid;
    int len = lens[b];
    const float* xg = (dir ? xgb : xgf) + (size_t)b * LL * 512;
    const float* wT = wt_all + (size_t)(dir ? 3 : 1) * 65536;  // seqf_hh / seqb_hh transposed
    int tid = threadIdx.x;
    float w[128];
#pragma unroll
    for (int k = 0; k < 128; ++k) w[k] = wT[k * 512 + tid];
    __shared__ __align__(16) float hsh[128];
    __shared__ __align__(16) float gsh[512];
    float cj = 0.f;
    if (tid < 128) hsh[tid] = 0.f;
    __syncthreads();
    for (int t = 0; t < len; ++t) {
        float acc = xg[(size_t)t * 512 + tid];
#pragma unroll
        for (int k4 = 0; k4 < 32; ++k4) {
            float4 hv = *(const float4*)&hsh[k4 * 4];
            acc += hv.x * w[k4 * 4] + hv.y * w[k4 * 4 + 1] + hv.z * w[k4 * 4 + 2] + hv.w * w[k4 * 4 + 3];
        }
        gsh[tid] = acc;
        __syncthreads();
        if (tid < 128) {
            float i_ = gsh[tid], f_ = gsh[128 + tid], g_ = gsh[256 + tid], o_ = gsh[384 + tid];
            cj = sigm(f_) * cj + sigm(i_) * tanhf(g_);
            float hv2 = sigm(o_) * tanhf(cj);
            hsh[tid] = hv2;
            int tout = dir ? (len - 1 - t) : t;
            senc[((size_t)b * LL + tout) * 256 + dir * 128 + tid] = hv2;
        }
        __syncthreads();
    }
}

// ---------------- mask + zero-invalid + max_len ----------------
__global__ __launch_bounds__(256) void finalize_k(const int* __restrict__ idx,
                                                  const int* __restrict__ lens,
                                                  float* __restrict__ senc,
                                                  float* __restrict__ mask,
                                                  float* __restrict__ omax,
                                                  const int* __restrict__ mlin)
{
    int t = blockIdx.x * 256 + threadIdx.x;
    if (t == 0) omax[0] = (float)mlin[0];
    if (t >= BB * LL) return;
    int b = t / LL, tt = t % LL;
    mask[t] = (idx[t] == 0) ? 1.f : 0.f;
    if (tt >= lens[b]) {
        float* row = senc + (size_t)t * 256;
        for (int j = 0; j < 256; ++j) row[j] = 0.f;
    }
}

// ---------------- gated-attention context: one wave per node ----------------
template<int D>
__global__ __launch_bounds__(256) void attn_ctx_k(const float* __restrict__ hid,
                                                  const int* __restrict__ adj,
                                                  const float* __restrict__ att0,
                                                  const float* __restrict__ att1,
                                                  float* __restrict__ ctx)
{
    constexpr int C = D / 64;
    int lane = threadIdx.x & 63, wid = threadIdx.x >> 6;
    int n = blockIdx.x * 4 + wid;
    if (n >= NN) return;
    float a0[C], a1[C], sv[C];
#pragma unroll
    for (int j = 0; j < C; ++j) {
        a0[j] = att0[lane + 64 * j];
        a1[j] = att1[lane + 64 * j];
        sv[j] = hid[(size_t)n * D + lane + 64 * j];
    }
    float p = 0.f;
#pragma unroll
    for (int j = 0; j < C; ++j) p += sv[j] * a0[j];
#pragma unroll
    for (int m = 1; m < 64; m <<= 1) p += __shfl_xor(p, m);
    float s_self = p;
    float nv[KNB][C];
    float sc[KNB];
#pragma unroll
    for (int k = 0; k < KNB; ++k) {
        int nb = adj[n * KNB + k];
        float q = 0.f;
#pragma unroll
        for (int j = 0; j < C; ++j) {
            float v = (nb < NN) ? hid[(size_t)nb * D + lane + 64 * j] : 0.f;
            nv[k][j] = v;
            q += v * a1[j];
        }
#pragma unroll
        for (int m = 1; m < 64; m <<= 1) q += __shfl_xor(q, m);
        sc[k] = s_self + q;
    }
    float mx = sc[0];
#pragma unroll
    for (int k = 1; k < KNB; ++k) mx = fmaxf(mx, sc[k]);
    float s = 0.f;
#pragma unroll
    for (int k = 0; k < KNB; ++k) { sc[k] = expf(sc[k] - mx); s += sc[k]; }
    float inv = 1.f / s;
#pragma unroll
    for (int j = 0; j < C; ++j) {
        float cv = 0.f;
#pragma unroll
        for (int k = 0; k < KNB; ++k) cv += sc[k] * nv[k][j];
        ctx[(size_t)n * D + lane + 64 * j] = cv * inv;
    }
}

// ---------------- graph max pool ----------------
__global__ __launch_bounds__(512) void gmax_k(const float* __restrict__ gh, float* __restrict__ ge)
{
    int g = blockIdx.x;
    int c = threadIdx.x;
    const float* p = gh + (size_t)g * 1000 * 512 + c;
    float m = -1e30f;
    for (int i = 0; i < 1000; ++i) m = fmaxf(m, p[(size_t)i * 512]);
    ge[g * 512 + c] = m;
}

extern "C" void kernel_launch(void* const* d_in, const int* in_sizes, int n_in,
                              void* d_out, int out_size, void* d_ws, size_t ws_size,
                              hipStream_t stream)
{
    const float* embed = (const float*)d_in[0];
    const float* sfWih = (const float*)d_in[1];
    const float* sfWhh = (const float*)d_in[2];
    const float* sfb   = (const float*)d_in[3];
    const float* sbWih = (const float*)d_in[4];
    const float* sbWhh = (const float*)d_in[5];
    const float* sbb   = (const float*)d_in[6];
    const float* ndWih = (const float*)d_in[7];
    const float* ndWhh = (const float*)d_in[8];
    const float* ndb   = (const float*)d_in[9];
    const int* nodefeat = (const int*)d_in[30];
    const int* adjs[2]  = {(const int*)d_in[31], (const int*)d_in[32]};
    const int* idxseq   = (const int*)d_in[33];
    const int* lens     = (const int*)d_in[34];
    const int* mlin     = (const int*)d_in[35];

    // workspace layout (floats), phase-aliased: total 29,353,216 floats (~117 MB)
    float* ws  = (float*)d_ws;
    float* wt  = ws;                    // 393216: 6 transposed (128,512) weights
    float* hn  = wt + 393216;           // 3,200,000 node h / node_embedding
    float* S1  = hn + 3200000;          // 6,560,000 (phase1: xgf|xgb|tokrev; phase2: cn; phase3: HA)
    float* S2  = S1 + 6560000;          // 12,800,000 (phase2: G; phase3: ctx|gctx)
    float* HB  = S2 + 12800000;         // 6,400,000
    float* xgf = S1;
    float* xgb = S1 + 3276800;
    int* tokrev = (int*)(S1 + 6553600);
    float* cn  = S1;
    float* HA  = S1;
    float* G   = S2;
    float* ctx = S2;
    float* gctx = S2 + 6400000;

    float* outf  = (float*)d_out;
    float* gh    = outf;                 // 12,800,000
    float* ge    = outf + 12800000;      // 12,800
    float* omax  = outf + 12812800;      // 1
    float* senc  = outf + 12812801;      // 1,638,400
    float* omask = outf + 14451201;      // 6,400

    // phase 0: weight transposes + reversed-token gather index
    transpose6_k<<<dim3((6 * 65536) / 256), dim3(256), 0, stream>>>(sfWih, sfWhh, sbWih, sbWhh, ndWih, ndWhh, wt);
    tokrev_k<<<dim3((BB * LL + 255) / 256), dim3(256), 0, stream>>>(idxseq, lens, tokrev);

    // phase 1: sequence bi-LSTM
    sgemm_k<1, 0><<<dim3(50, 4), dim3(256), 0, stream>>>(embed, 128, idxseq, 1, 0, nullptr,
        wt + 0 * 65536, 512, sfb, nullptr, 0, xgf, 512, 0, BB * LL, 512, 128);
    sgemm_k<1, 0><<<dim3(50, 4), dim3(256), 0, stream>>>(embed, 128, tokrev, 1, 0, nullptr,
        wt + 2 * 65536, 512, sbb, nullptr, 0, xgb, 512, 0, BB * LL, 512, 128);
    seq_lstm_k<<<dim3(2 * BB), dim3(512), 0, stream>>>(xgf, xgb, wt, lens, senc);
    finalize_k<<<dim3((BB * LL + 255) / 256), dim3(256), 0, stream>>>(idxseq, lens, senc, omask, omax, mlin);

    // phase 2: node LSTM (4 steps)
    zero_k<<<dim3((3200000 + 255) / 256), dim3(256), 0, stream>>>(hn, 3200000);
    zero_k<<<dim3((3200000 + 255) / 256), dim3(256), 0, stream>>>(cn, 3200000);
    for (int t = 0; t < NTK; ++t) {
        sgemm_k<2, 0><<<dim3(196, 4), dim3(256), 0, stream>>>(embed, 128, nodefeat, NTK, t, hn,
            wt + 4 * 65536, 512, ndb, nullptr, 0, G, 512, 0, NN, 512, 256);
        lstm_cell_k<<<dim3((NN * HH + 255) / 256), dim3(256), 0, stream>>>(G, hn, cn, NN);
    }

    // phase 3: graph attention layers (fw fully, then bw; ping-pong hn->HA->HB->gh)
    for (int dir = 0; dir < 2; ++dir) {
        int base = 10 + dir * 10;
        const float* att0w = (const float*)d_in[base + 0];
        const float* attrw = (const float*)d_in[base + 1];
        const float* Wg0   = (const float*)d_in[base + 2];
        const float* bg0   = (const float*)d_in[base + 3];
        const float* Wgr   = (const float*)d_in[base + 4];
        const float* bgr   = (const float*)d_in[base + 5];
        const float* Wo0   = (const float*)d_in[base + 6];
        const float* bo0   = (const float*)d_in[base + 7];
        const float* Wor   = (const float*)d_in[base + 8];
        const float* bor   = (const float*)d_in[base + 9];
        const int* adj = adjs[dir];
        for (int l = 0; l < 3; ++l) {
            int D = (l == 0) ? 128 : 256;
            const float* cur = (l == 0) ? hn : (l == 1 ? HA : HB);
            const float* a0 = (l == 0) ? att0w : attrw + (size_t)(l - 1) * 2 * 256;
            const float* a1 = (l == 0) ? att0w + 128 : attrw + (size_t)(l - 1) * 2 * 256 + 256;
            const float* Wg = (l == 0) ? Wg0 : Wgr + (size_t)(l - 1) * 256 * 256;
            const float* bg = (l == 0) ? bg0 : bgr + (size_t)(l - 1) * 256;
            const float* Wos = (l == 0) ? Wo0 : Wor + (size_t)(l - 1) * 2 * 256 * 128;
            const float* Won = (l == 0) ? Wo0 + 128 * 128 : Wor + (size_t)(l - 1) * 2 * 256 * 128 + 256 * 128;
            const float* bos = (l == 0) ? bo0 : bor + (size_t)(l - 1) * 2 * 128;
            const float* bon = (l == 0) ? bo0 + 128 : bor + (size_t)(l - 1) * 2 * 128 + 128;
            float* ob;
            int ldo, oc;
            if (l == 2) { ob = gh; ldo = 512; oc = dir * 256; }
            else        { ob = (l == 0) ? HA : HB; ldo = 256; oc = 0; }

            if (D == 128)
                attn_ctx_k<128><<<dim3(NN / 4), dim3(256), 0, stream>>>(cur, adj, a0, a1, ctx);
            else
                attn_ctx_k<256><<<dim3(NN / 4), dim3(256), 0, stream>>>(cur, adj, a0, a1, ctx);
            // gctx = sigmoid(cur@Wg+bg) * ctx
            sgemm_k<0, 2><<<dim3(196, D / 128), dim3(256), 0, stream>>>(cur, D, nullptr, 0, 0, nullptr,
                Wg, D, bg, ctx, D, gctx, D, 0, NN, D, D);
            // from_self = relu(cur@Wo[0]+bo[0])
            sgemm_k<0, 1><<<dim3(196, 1), dim3(256), 0, stream>>>(cur, D, nullptr, 0, 0, nullptr,
                Wos, 128, bos, nullptr, 0, ob, ldo, oc, NN, 128, D);
            // from_neigh = relu(gctx@Wo[1]+bo[1])
            sgemm_k<0, 1><<<dim3(196, 1), dim3(256), 0, stream>>>(gctx, D, nullptr, 0, 0, nullptr,
                Won, 128, bon, nullptr, 0, ob, ldo, oc + 128, NN, 128, D);
        }
    }

    // phase 4: graph embedding max-pool
    gmax_k<<<dim3(NGRAPH), dim3(512), 0, stream>>>(gh, ge);
}

// Round 2
// 1395.859 us; speedup vs baseline: 1.4725x; 1.4725x over previous
//
#include <hip/hip_runtime.h>
#include <math.h>

#define NN 25000
#define KNB 16
#define HH 128
#define VV 32000
#define BB 50
#define LL 128
#define NTK 4
#define NGRAPH 25

typedef __attribute__((ext_vector_type(8))) short s16x8;
typedef __attribute__((ext_vector_type(4))) float f32x4;

__device__ __forceinline__ float sigm(float x) { return 1.f / (1.f + expf(-x)); }

__device__ __forceinline__ unsigned short f2bf(float x) {
    unsigned int u = __float_as_uint(x);
    unsigned int r = (u + 0x7fffu + ((u >> 16) & 1u)) >> 16;
    return (unsigned short)r;
}
__device__ __forceinline__ float bf2f(unsigned int b) {
    return __uint_as_float((b & 0xffffu) << 16);
}

// ---------------- transpose 4 seq LSTM weights (512,128)->(128,512) f32 ----------------
__global__ __launch_bounds__(256) void transpose4_k(
    const float* __restrict__ s0, const float* __restrict__ s1,
    const float* __restrict__ s2, const float* __restrict__ s3,
    float* __restrict__ dst)
{
    int t = blockIdx.x * 256 + threadIdx.x;
    if (t >= 4 * 65536) return;
    int mat = t >> 16, r = t & 65535;
    int k = r >> 9, g = r & 511;
    const float* s = mat == 0 ? s0 : mat == 1 ? s1 : mat == 2 ? s2 : s3;
    dst[t] = s[g * 128 + k];
}

__global__ __launch_bounds__(256) void zero_k(float* __restrict__ p, int n)
{
    int i = blockIdx.x * 256 + threadIdx.x;
    if (i < n) p[i] = 0.f;
}

// ---------------- embed f32 -> bf16 ----------------
__global__ __launch_bounds__(256) void embconv_k(const float* __restrict__ e,
                                                 unsigned short* __restrict__ o)
{
    int i = blockIdx.x * 256 + threadIdx.x;
    if (i < VV * 128) o[i] = f2bf(e[i]);
}

// ---------------- weight prep: convert+transpose graph/node weights to bf16 [N][K] ----------------
// arena layout (ushort elems):
//   nodeWt [512][256] @ 0                       (131072)
//   per dir wb = 131072 + dir*311296:
//     wg0t  [128][128] @ wb+0
//     wgrt  [256][256] @ wb+16384 + j*65536   (j=0,1)
//     wo0st [128][128] @ wb+147456 ; wo0nt @ wb+163840
//     wort  [128][256] @ wb+180224 + (j*2+s)*32768
__global__ __launch_bounds__(256) void wprep_k(
    const float* __restrict__ ndWih, const float* __restrict__ ndWhh,
    const float* __restrict__ fWg0, const float* __restrict__ fWgr,
    const float* __restrict__ fWo0, const float* __restrict__ fWor,
    const float* __restrict__ bWg0, const float* __restrict__ bWgr,
    const float* __restrict__ bWo0, const float* __restrict__ bWor,
    unsigned short* __restrict__ dst)
{
    int idx = blockIdx.x * 256 + threadIdx.x;
    if (idx >= 753664) return;
    float val;
    if (idx < 131072) {
        int g = idx >> 8, k = idx & 255;
        val = (k < 128) ? ndWih[g * 128 + k] : ndWhh[g * 128 + (k - 128)];
    } else {
        int r = idx - 131072;
        int dir = r / 311296;
        int o = r % 311296;
        const float* Wg0 = dir ? bWg0 : fWg0;
        const float* Wgr = dir ? bWgr : fWgr;
        const float* Wo0 = dir ? bWo0 : fWo0;
        const float* Wor = dir ? bWor : fWor;
        if (o < 16384) {
            int n = o >> 7, k = o & 127;
            val = Wg0[k * 128 + n];
        } else if (o < 147456) {
            int p = o - 16384;
            int j = p >> 16, q = p & 65535;
            int n = q >> 8, k = q & 255;
            val = Wgr[j * 65536 + k * 256 + n];
        } else if (o < 180224) {
            int p = o - 147456;
            int s = p >> 14, q = p & 16383;
            int n = q >> 7, k = q & 127;
            val = Wo0[s * 16384 + k * 128 + n];
        } else {
            int p = o - 180224;
            int js = p >> 15, q = p & 32767;
            int n = q >> 8, k = q & 255;
            val = Wor[js * 32768 + k * 128 + n];
        }
    }
    dst[idx] = f2bf(val);
}

__global__ __launch_bounds__(256) void tokrev_k(const int* __restrict__ idx,
                                                const int* __restrict__ lens,
                                                int* __restrict__ tokrev)
{
    int t = blockIdx.x * 256 + threadIdx.x;
    if (t >= BB * LL) return;
    int b = t / LL, tt = t % LL;
    int r = lens[b] - 1 - tt;
    r = r < 0 ? 0 : (r > LL - 1 ? LL - 1 : r);
    tokrev[t] = idx[b * LL + r];
}

// ---------------- f32 GEMM (kept for seq xg): C[m,n] = A[gidx[m]]@W + b ----------------
__global__ __launch_bounds__(256) void sgemm_g_k(
    const float* __restrict__ A,
    const int* __restrict__ gidx,
    const float* __restrict__ W, int ldw,
    const float* __restrict__ bias,
    float* __restrict__ out, int ldo,
    int M, int N, int K)
{
    __shared__ __align__(16) float As[16 * 132];
    __shared__ __align__(16) float Bs[16 * 136];
    const int tid = threadIdx.x;
    const int bm0 = blockIdx.x * 128;
    const int bn0 = blockIdx.y * 128;
    const int tx = tid & 15, ty = tid >> 4;
    float acc[8][8];
#pragma unroll
    for (int i = 0; i < 8; ++i)
#pragma unroll
        for (int j = 0; j < 8; ++j) acc[i][j] = 0.f;

    for (int kt = 0; kt < K; kt += 16) {
#pragma unroll
        for (int rep = 0; rep < 2; ++rep) {
            int id = tid + rep * 256;
            int row = id >> 2, kq = id & 3;
            int m = bm0 + row, k = kt + kq * 4;
            float4 av = make_float4(0.f, 0.f, 0.f, 0.f);
            if (m < M) {
                int g = gidx[m];
                av = *(const float4*)(A + (size_t)g * 128 + k);
            }
            As[(kq * 4 + 0) * 132 + row] = av.x;
            As[(kq * 4 + 1) * 132 + row] = av.y;
            As[(kq * 4 + 2) * 132 + row] = av.z;
            As[(kq * 4 + 3) * 132 + row] = av.w;
        }
#pragma unroll
        for (int rep = 0; rep < 2; ++rep) {
            int id = tid + rep * 256;
            int kr = id >> 5, n4 = id & 31;
            float4 bv = *(const float4*)(W + (size_t)(kt + kr) * ldw + bn0 + n4 * 4);
            *(float4*)&Bs[kr * 136 + n4 * 4] = bv;
        }
        __syncthreads();
#pragma unroll
        for (int k = 0; k < 16; ++k) {
            float4 aA = *(const float4*)&As[k * 132 + ty * 8];
            float4 aB = *(const float4*)&As[k * 132 + ty * 8 + 4];
            float4 bA = *(const float4*)&Bs[k * 136 + tx * 8];
            float4 bB = *(const float4*)&Bs[k * 136 + tx * 8 + 4];
            float a[8] = {aA.x, aA.y, aA.z, aA.w, aB.x, aB.y, aB.z, aB.w};
            float b[8] = {bA.x, bA.y, bA.z, bA.w, bB.x, bB.y, bB.z, bB.w};
#pragma unroll
            for (int i = 0; i < 8; ++i)
#pragma unroll
                for (int j = 0; j < 8; ++j) acc[i][j] += a[i] * b[j];
        }
        __syncthreads();
    }
#pragma unroll
    for (int i = 0; i < 8; ++i) {
        int m = bm0 + ty * 8 + i;
        if (m < M) {
#pragma unroll
            for (int j = 0; j < 8; ++j) {
                int n = bn0 + tx * 8 + j;
                out[(size_t)m * ldo + n] = acc[i][j] + bias[n];
            }
        }
    }
}

// ---------------- bf16 MFMA GEMM ----------------
// AMODE 0: A[m*lda+k] bf16; 2: k<128 -> embed_bf[gidx[m*gs+go]*128+k] else H2[m*128+k-128]
// EP 0: none; 1: relu; 2: sigmoid(v)*aux_bf16[m*ldaux+n]
// OF32 1: out f32, 0: out bf16
template<int AMODE, int EP, int OF32>
__global__ __launch_bounds__(256) void hgemm_k(
    const unsigned short* __restrict__ A, int lda,
    const int* __restrict__ gidx, int gstride, int goff,
    const unsigned short* __restrict__ H2,
    const unsigned short* __restrict__ Wt,   // [N][K] bf16
    const float* __restrict__ bias,
    const unsigned short* __restrict__ aux, int ldaux,
    void* __restrict__ outp, int ldo, int ocol,
    int M, int N, int K)
{
    __shared__ unsigned short Asm[128 * 64];
    __shared__ unsigned short Bsm[128 * 64];
    const int tid = threadIdx.x;
    const int lane = tid & 63, w = tid >> 6;
    const int wm = w >> 1, wn = w & 1;
    const int bm0 = blockIdx.x * 128, bn0 = blockIdx.y * 128;
    f32x4 acc[4][4];
#pragma unroll
    for (int i = 0; i < 4; ++i)
#pragma unroll
        for (int j = 0; j < 4; ++j) acc[i][j] = (f32x4){0.f, 0.f, 0.f, 0.f};

    for (int kt = 0; kt < K; kt += 64) {
        // stage A tile [128 rows][64 k] with XOR swizzle
#pragma unroll
        for (int r = 0; r < 4; ++r) {
            int id = tid + r * 256;
            int row = id >> 3, cc = id & 7;
            int m = bm0 + row;
            s16x8 v = {0, 0, 0, 0, 0, 0, 0, 0};
            if (m < M) {
                const unsigned short* src;
                if (AMODE == 0) {
                    src = A + (size_t)m * lda + kt + cc * 8;
                } else {
                    int k0 = kt + cc * 8;
                    if (k0 < 128) {
                        int g = gidx[m * gstride + goff];
                        src = A + (size_t)g * 128 + k0;
                    } else {
                        src = H2 + (size_t)m * 128 + (k0 - 128);
                    }
                }
                v = *(const s16x8*)src;
            }
            int byt = (cc * 16) ^ ((row & 7) << 4);
            *(s16x8*)((char*)Asm + row * 128 + byt) = v;
        }
        // stage B tile [128 n][64 k]
#pragma unroll
        for (int r = 0; r < 4; ++r) {
            int id = tid + r * 256;
            int row = id >> 3, cc = id & 7;
            s16x8 v = *(const s16x8*)(Wt + (size_t)(bn0 + row) * K + kt + cc * 8);
            int byt = (cc * 16) ^ ((row & 7) << 4);
            *(s16x8*)((char*)Bsm + row * 128 + byt) = v;
        }
        __syncthreads();
#pragma unroll
        for (int ks = 0; ks < 2; ++ks) {
            s16x8 af[4], bf[4];
#pragma unroll
            for (int mi = 0; mi < 4; ++mi) {
                int row = wm * 64 + mi * 16 + (lane & 15);
                int byt = (ks * 64 + ((lane >> 4) * 16)) ^ ((row & 7) << 4);
                af[mi] = *(const s16x8*)((char*)Asm + row * 128 + byt);
            }
#pragma unroll
            for (int ni = 0; ni < 4; ++ni) {
                int row = wn * 64 + ni * 16 + (lane & 15);
                int byt = (ks * 64 + ((lane >> 4) * 16)) ^ ((row & 7) << 4);
                bf[ni] = *(const s16x8*)((char*)Bsm + row * 128 + byt);
            }
#pragma unroll
            for (int mi = 0; mi < 4; ++mi)
#pragma unroll
                for (int ni = 0; ni < 4; ++ni)
                    acc[mi][ni] = __builtin_amdgcn_mfma_f32_16x16x32_bf16(af[mi], bf[ni], acc[mi][ni], 0, 0, 0);
        }
        __syncthreads();
    }
    // epilogue: C/D layout col=lane&15, row=(lane>>4)*4+j
#pragma unroll
    for (int mi = 0; mi < 4; ++mi) {
#pragma unroll
        for (int ni = 0; ni < 4; ++ni) {
            int n = bn0 + wn * 64 + ni * 16 + (lane & 15);
#pragma unroll
            for (int j = 0; j < 4; ++j) {
                int m = bm0 + wm * 64 + mi * 16 + (lane >> 4) * 4 + j;
                if (m < M) {
                    float v = acc[mi][ni][j] + bias[n];
                    if (EP == 1) v = fmaxf(v, 0.f);
                    if (EP == 2) v = sigm(v) * bf2f(aux[(size_t)m * ldaux + n]);
                    if (OF32) ((float*)outp)[(size_t)m * ldo + ocol + n] = v;
                    else ((unsigned short*)outp)[(size_t)m * ldo + ocol + n] = f2bf(v);
                }
            }
        }
    }
}

// ---------------- node LSTM cell: h out as bf16, c stays f32 ----------------
__global__ __launch_bounds__(256) void lstm_cell_k(const float* __restrict__ G,
                                                   unsigned short* __restrict__ hb,
                                                   float* __restrict__ c, int M)
{
    int i = blockIdx.x * 256 + threadIdx.x;
    if (i >= M * HH) return;
    int m = i >> 7, j = i & 127;
    const float* g = G + (size_t)m * 512;
    float i_ = g[j], f_ = g[128 + j], gg = g[256 + j], o_ = g[384 + j];
    float cc = c[i];
    cc = sigm(f_) * cc + sigm(i_) * tanhf(gg);
    float hh = sigm(o_) * tanhf(cc);
    c[i] = cc;
    hb[i] = f2bf(hh);
}

// ---------------- per-sequence LSTM recurrence ----------------
__global__ __launch_bounds__(512) void seq_lstm_k(const float* __restrict__ xgf,
                                                  const float* __restrict__ xgb,
                                                  const float* __restrict__ wt_all,
                                                  const int* __restrict__ lens,
                                                  float* __restrict__ senc)
{
    int bid = blockIdx.x;
    int dir = bid >= BB ? 1 : 0;
    int b = dir ? bid - BB : bid;
    int len = lens[b];
    const float* xg = (dir ? xgb : xgf) + (size_t)b * LL * 512;
    const float* wT = wt_all + (size_t)(dir ? 3 : 1) * 65536;
    int tid = threadIdx.x;
    int gate = tid >> 7;
    float wreg[128];
#pragma unroll
    for (int k = 0; k < 128; ++k) wreg[k] = wT[k * 512 + tid];
    __shared__ __align__(16) float hsh[128];
    __shared__ __align__(16) float gsh[512];
    float cj = 0.f;
    if (tid < 128) hsh[tid] = 0.f;
    __syncthreads();
    float xcur = xg[tid];
    for (int t = 0; t < len; ++t) {
        float xnext = (t + 1 < len) ? xg[(size_t)(t + 1) * 512 + tid] : 0.f;
        float acc = xcur;
#pragma unroll
        for (int k4 = 0; k4 < 32; ++k4) {
            float4 hv = *(const float4*)&hsh[k4 * 4];
            acc += hv.x * wreg[k4 * 4] + hv.y * wreg[k4 * 4 + 1] + hv.z * wreg[k4 * 4 + 2] + hv.w * wreg[k4 * 4 + 3];
        }
        // apply per-gate nonlinearity in the wide phase (gate 2 = tanh, others sigmoid)
        float tv = (gate == 2) ? tanhf(acc) : sigm(acc);
        gsh[tid] = tv;
        __syncthreads();
        if (tid < 128) {
            float i_ = gsh[tid], f_ = gsh[128 + tid], g_ = gsh[256 + tid], o_ = gsh[384 + tid];
            cj = f_ * cj + i_ * g_;
            float hv2 = o_ * tanhf(cj);
            hsh[tid] = hv2;
            int tout = dir ? (len - 1 - t) : t;
            senc[((size_t)b * LL + tout) * 256 + dir * 128 + tid] = hv2;
        }
        __syncthreads();
        xcur = xnext;
    }
}

// ---------------- mask + zero-invalid + max_len ----------------
__global__ __launch_bounds__(256) void finalize_k(const int* __restrict__ idx,
                                                  const int* __restrict__ lens,
                                                  float* __restrict__ senc,
                                                  float* __restrict__ mask,
                                                  float* __restrict__ omax,
                                                  const int* __restrict__ mlin)
{
    int t = blockIdx.x * 256 + threadIdx.x;
    if (t == 0) omax[0] = (float)mlin[0];
    if (t >= BB * LL) return;
    int b = t / LL, tt = t % LL;
    mask[t] = (idx[t] == 0) ? 1.f : 0.f;
    if (tt >= lens[b]) {
        float* row = senc + (size_t)t * 256;
        for (int j = 0; j < 256; ++j) row[j] = 0.f;
    }
}

// ---------------- gated-attention context (bf16 in, bf16 out) ----------------
template<int D>
__global__ __launch_bounds__(256) void attn_ctx_k(const unsigned short* __restrict__ hid,
                                                  const int* __restrict__ adj,
                                                  const float* __restrict__ att0,
                                                  const float* __restrict__ att1,
                                                  unsigned short* __restrict__ ctx)
{
    constexpr int V = D / 64;   // 2 or 4 consecutive elems per lane
    int lane = threadIdx.x & 63, wid = threadIdx.x >> 6;
    int n = blockIdx.x * 4 + wid;
    if (n >= NN) return;
    float a0[V], a1[V], sv[V];
#pragma unroll
    for (int j = 0; j < V; ++j) {
        a0[j] = att0[lane * V + j];
        a1[j] = att1[lane * V + j];
    }
    {
        if (V == 2) {
            unsigned int u = *(const unsigned int*)(hid + (size_t)n * D + lane * 2);
            sv[0] = bf2f(u); sv[1] = bf2f(u >> 16);
        } else {
            uint2 u = *(const uint2*)(hid + (size_t)n * D + lane * 4);
            sv[0] = bf2f(u.x); sv[1] = bf2f(u.x >> 16);
            sv[2] = bf2f(u.y); sv[3] = bf2f(u.y >> 16);
        }
    }
    float p = 0.f;
#pragma unroll
    for (int j = 0; j < V; ++j) p += sv[j] * a0[j];
#pragma unroll
    for (int m = 1; m < 64; m <<= 1) p += __shfl_xor(p, m);
    float s_self = p;
    float nv[KNB][V];
    float sc[KNB];
#pragma unroll
    for (int k = 0; k < KNB; ++k) {
        int nb = adj[n * KNB + k];
        float q = 0.f;
        if (nb < NN) {
            if (V == 2) {
                unsigned int u = *(const unsigned int*)(hid + (size_t)nb * D + lane * 2);
                nv[k][0] = bf2f(u); nv[k][1] = bf2f(u >> 16);
            } else {
                uint2 u = *(const uint2*)(hid + (size_t)nb * D + lane * 4);
                nv[k][0] = bf2f(u.x); nv[k][1] = bf2f(u.x >> 16);
                nv[k][2] = bf2f(u.y); nv[k][3] = bf2f(u.y >> 16);
            }
        } else {
#pragma unroll
            for (int j = 0; j < V; ++j) nv[k][j] = 0.f;
        }
#pragma unroll
        for (int j = 0; j < V; ++j) q += nv[k][j] * a1[j];
#pragma unroll
        for (int m = 1; m < 64; m <<= 1) q += __shfl_xor(q, m);
        sc[k] = s_self + q;
    }
    float mx = sc[0];
#pragma unroll
    for (int k = 1; k < KNB; ++k) mx = fmaxf(mx, sc[k]);
    float s = 0.f;
#pragma unroll
    for (int k = 0; k < KNB; ++k) { sc[k] = expf(sc[k] - mx); s += sc[k]; }
    float inv = 1.f / s;
#pragma unroll
    for (int j2 = 0; j2 < V; j2 += 2) {
        float c0 = 0.f, c1 = 0.f;
#pragma unroll
        for (int k = 0; k < KNB; ++k) { c0 += sc[k] * nv[k][j2]; c1 += sc[k] * nv[k][j2 + 1]; }
        unsigned int pk = (unsigned int)f2bf(c0 * inv) | ((unsigned int)f2bf(c1 * inv) << 16);
        *(unsigned int*)(ctx + (size_t)n * D + lane * V + j2) = pk;
    }
}

// ---------------- graph max pool ----------------
__global__ __launch_bounds__(512) void gmax_k(const float* __restrict__ gh, float* __restrict__ ge)
{
    int g = blockIdx.x;
    int c = threadIdx.x;
    const float* p = gh + (size_t)g * 1000 * 512 + c;
    float m = -1e30f;
    for (int i = 0; i < 1000; ++i) m = fmaxf(m, p[(size_t)i * 512]);
    ge[g * 512 + c] = m;
}

extern "C" void kernel_launch(void* const* d_in, const int* in_sizes, int n_in,
                              void* d_out, int out_size, void* d_ws, size_t ws_size,
                              hipStream_t stream)
{
    const float* embed = (const float*)d_in[0];
    const float* sfWih = (const float*)d_in[1];
    const float* sfWhh = (const float*)d_in[2];
    const float* sfb   = (const float*)d_in[3];
    const float* sbWih = (const float*)d_in[4];
    const float* sbWhh = (const float*)d_in[5];
    const float* sbb   = (const float*)d_in[6];
    const float* ndWih = (const float*)d_in[7];
    const float* ndWhh = (const float*)d_in[8];
    const float* ndb   = (const float*)d_in[9];
    const int* nodefeat = (const int*)d_in[30];
    const int* adjs[2]  = {(const int*)d_in[31], (const int*)d_in[32]};
    const int* idxseq   = (const int*)d_in[33];
    const int* lens     = (const int*)d_in[34];
    const int* mlin     = (const int*)d_in[35];

    // ---- workspace layout (f32 units), phase-aliased; total 23,646,976 f32 = 94.6 MB ----
    float* ws   = (float*)d_ws;
    float* wt   = ws;                         // 262,144 : 4 seq weights f32 transposed
    float* P1   = ws + 262144;                // 6,560,000
    float* xgf  = P1;
    float* xgb  = P1 + 3276800;
    int*   tokrev = (int*)(P1 + 6553600);
    float* cn   = P1;                         // phase 2 cell state (3,200,000)
    unsigned short* HA = (unsigned short*)P1;               // phase 3: 6.4M ushorts
    unsigned short* HB = (unsigned short*)(P1 + 3200000);   // 6.4M ushorts
    unsigned short* embedbf = (unsigned short*)(ws + 6822144);   // 4,096,000 us
    unsigned short* warena  = (unsigned short*)(ws + 8870144);   // 753,664 us
    unsigned short* hbf     = (unsigned short*)(ws + 9246976);   // 3,200,000 us
    float* G    = ws + 10846976;              // 12,800,000
    unsigned short* ctxb  = (unsigned short*)G;                  // phase 3: 6.4M us
    unsigned short* gctxb = (unsigned short*)(G + 3200000);      // 6.4M us

    float* outf  = (float*)d_out;
    float* gh    = outf;                 // 12,800,000
    float* ge    = outf + 12800000;      // 12,800
    float* omax  = outf + 12812800;      // 1
    float* senc  = outf + 12812801;      // 1,638,400
    float* omask = outf + 14451201;      // 6,400

    // phase 0: preps (independent)
    transpose4_k<<<dim3(1024), dim3(256), 0, stream>>>(sfWih, sfWhh, sbWih, sbWhh, wt);
    tokrev_k<<<dim3((BB * LL + 255) / 256), dim3(256), 0, stream>>>(idxseq, lens, tokrev);
    embconv_k<<<dim3(VV * 128 / 256), dim3(256), 0, stream>>>(embed, embedbf);
    wprep_k<<<dim3(2944), dim3(256), 0, stream>>>(ndWih, ndWhh,
        (const float*)d_in[12], (const float*)d_in[14], (const float*)d_in[16], (const float*)d_in[18],
        (const float*)d_in[22], (const float*)d_in[24], (const float*)d_in[26], (const float*)d_in[28],
        warena);

    // phase 1: sequence bi-LSTM (f32)
    sgemm_g_k<<<dim3(50, 4), dim3(256), 0, stream>>>(embed, idxseq, wt + 0 * 65536, 512, sfb, xgf, 512, BB * LL, 512, 128);
    sgemm_g_k<<<dim3(50, 4), dim3(256), 0, stream>>>(embed, tokrev, wt + 2 * 65536, 512, sbb, xgb, 512, BB * LL, 512, 128);
    seq_lstm_k<<<dim3(2 * BB), dim3(512), 0, stream>>>(xgf, xgb, wt, lens, senc);
    finalize_k<<<dim3((BB * LL + 255) / 256), dim3(256), 0, stream>>>(idxseq, lens, senc, omask, omax, mlin);

    // phase 2: node LSTM (4 steps), bf16 MFMA GEMM
    zero_k<<<dim3((3200000 + 255) / 256), dim3(256), 0, stream>>>(cn, 3200000);
    zero_k<<<dim3((1600000 + 255) / 256), dim3(256), 0, stream>>>((float*)hbf, 1600000);
    for (int t = 0; t < NTK; ++t) {
        hgemm_k<2, 0, 1><<<dim3(196, 4), dim3(256), 0, stream>>>(embedbf, 0, nodefeat, NTK, t, hbf,
            warena, ndb, nullptr, 0, G, 512, 0, NN, 512, 256);
        lstm_cell_k<<<dim3(NN * HH / 256), dim3(256), 0, stream>>>(G, hbf, cn, NN);
    }

    // phase 3: graph attention layers
    for (int dir = 0; dir < 2; ++dir) {
        int base = 10 + dir * 10;
        const float* att0w = (const float*)d_in[base + 0];
        const float* attrw = (const float*)d_in[base + 1];
        const float* bg0   = (const float*)d_in[base + 3];
        const float* bgr   = (const float*)d_in[base + 5];
        const float* bo0   = (const float*)d_in[base + 7];
        const float* bor   = (const float*)d_in[base + 9];
        const int* adj = adjs[dir];
        const unsigned short* wb = warena + 131072 + dir * 311296;
        for (int l = 0; l < 3; ++l) {
            int D = (l == 0) ? 128 : 256;
            int j = l - 1;
            const unsigned short* cur = (l == 0) ? hbf : (l == 1 ? HA : HB);
            const float* a0 = (l == 0) ? att0w : attrw + (size_t)j * 512;
            const float* a1 = (l == 0) ? att0w + 128 : attrw + (size_t)j * 512 + 256;
            const unsigned short* wg  = (l == 0) ? wb : wb + 16384 + j * 65536;
            const unsigned short* wos = (l == 0) ? wb + 147456 : wb + 180224 + (j * 2 + 0) * 32768;
            const unsigned short* won = (l == 0) ? wb + 163840 : wb + 180224 + (j * 2 + 1) * 32768;
            const float* bg = (l == 0) ? bg0 : bgr + (size_t)j * 256;
            const float* bos = (l == 0) ? bo0 : bor + (size_t)j * 256;
            const float* bon = (l == 0) ? bo0 + 128 : bor + (size_t)j * 256 + 128;

            if (D == 128)
                attn_ctx_k<128><<<dim3(NN / 4), dim3(256), 0, stream>>>(cur, adj, a0, a1, ctxb);
            else
                attn_ctx_k<256><<<dim3(NN / 4), dim3(256), 0, stream>>>(cur, adj, a0, a1, ctxb);

            // gate: gctx = sigmoid(cur@Wg+bg) * ctx   (bf16 out)
            hgemm_k<0, 2, 0><<<dim3(196, D / 128), dim3(256), 0, stream>>>(cur, D, nullptr, 0, 0, nullptr,
                wg, bg, ctxb, D, gctxb, D, 0, NN, D, D);

            if (l == 2) {
                hgemm_k<0, 1, 1><<<dim3(196, 1), dim3(256), 0, stream>>>(cur, D, nullptr, 0, 0, nullptr,
                    wos, bos, nullptr, 0, gh, 512, dir * 256, NN, 128, D);
                hgemm_k<0, 1, 1><<<dim3(196, 1), dim3(256), 0, stream>>>(gctxb, D, nullptr, 0, 0, nullptr,
                    won, bon, nullptr, 0, gh, 512, dir * 256 + 128, NN, 128, D);
            } else {
                unsigned short* ob = (l == 0) ? HA : HB;
                hgemm_k<0, 1, 0><<<dim3(196, 1), dim3(256), 0, stream>>>(cur, D, nullptr, 0, 0, nullptr,
                    wos, bos, nullptr, 0, ob, 256, 0, NN, 128, D);
                hgemm_k<0, 1, 0><<<dim3(196, 1), dim3(256), 0, stream>>>(gctxb, D, nullptr, 0, 0, nullptr,
                    won, bon, nullptr, 0, ob, 256, 128, NN, 128, D);
            }
        }
    }

    // phase 4: graph embedding max-pool
    gmax_k<<<dim3(NGRAPH), dim3(512), 0, stream>>>(gh, ge);
}

// Round 3
// 1181.149 us; speedup vs baseline: 1.7401x; 1.1818x over previous
//
#include <hip/hip_runtime.h>
#include <math.h>

#define NN 25000
#define KNB 16
#define HH 128
#define VV 32000
#define BB 50
#define LL 128
#define NTK 4
#define NGRAPH 25
#define GCH 20

typedef __attribute__((ext_vector_type(8))) short s16x8;
typedef __attribute__((ext_vector_type(4))) float f32x4;

__device__ __forceinline__ float sigm(float x) { return 1.f / (1.f + expf(-x)); }

__device__ __forceinline__ unsigned short f2bf(float x) {
    unsigned int u = __float_as_uint(x);
    unsigned int r = (u + 0x7fffu + ((u >> 16) & 1u)) >> 16;
    return (unsigned short)r;
}
__device__ __forceinline__ float bf2f(unsigned int b) {
    return __uint_as_float((b & 0xffffu) << 16);
}

// ---------------- transpose 4 seq LSTM weights (512,128)->(128,512) f32 ----------------
__global__ __launch_bounds__(256) void transpose4_k(
    const float* __restrict__ s0, const float* __restrict__ s1,
    const float* __restrict__ s2, const float* __restrict__ s3,
    float* __restrict__ dst)
{
    int t = blockIdx.x * 256 + threadIdx.x;
    if (t >= 4 * 65536) return;
    int mat = t >> 16, r = t & 65535;
    int k = r >> 9, g = r & 511;
    const float* s = mat == 0 ? s0 : mat == 1 ? s1 : mat == 2 ? s2 : s3;
    dst[t] = s[g * 128 + k];
}

__global__ __launch_bounds__(256) void zero_k(float* __restrict__ p, int n)
{
    int i = blockIdx.x * 256 + threadIdx.x;
    if (i < n) p[i] = 0.f;
}

// ---------------- embed f32 -> bf16 ----------------
__global__ __launch_bounds__(256) void embconv_k(const float* __restrict__ e,
                                                 unsigned short* __restrict__ o)
{
    int i = blockIdx.x * 256 + threadIdx.x;
    if (i < VV * 128) o[i] = f2bf(e[i]);
}

// ---------------- weight prep: convert+transpose weights to bf16 [N][K] ----------------
// arena layout (ushort elems):
//   nodeWt [512][256] @ 0                       (131072)
//   per dir wb = 131072 + dir*311296:
//     wg0t  [128][128] @ wb+0
//     wgrt  [256][256] @ wb+16384 + j*65536   (j=0,1)
//     wo0st [128][128] @ wb+147456 ; wo0nt @ wb+163840
//     wort  [128][256] @ wb+180224 + (j*2+s)*32768
//   sfWih bf16 [512][128] @ 753664 ; sbWih @ 819200   (total 884736)
__global__ __launch_bounds__(256) void wprep_k(
    const float* __restrict__ ndWih, const float* __restrict__ ndWhh,
    const float* __restrict__ fWg0, const float* __restrict__ fWgr,
    const float* __restrict__ fWo0, const float* __restrict__ fWor,
    const float* __restrict__ bWg0, const float* __restrict__ bWgr,
    const float* __restrict__ bWo0, const float* __restrict__ bWor,
    const float* __restrict__ sfWih, const float* __restrict__ sbWih,
    unsigned short* __restrict__ dst)
{
    int idx = blockIdx.x * 256 + threadIdx.x;
    if (idx >= 884736) return;
    float val;
    if (idx < 131072) {
        int g = idx >> 8, k = idx & 255;
        val = (k < 128) ? ndWih[g * 128 + k] : ndWhh[g * 128 + (k - 128)];
    } else if (idx < 753664) {
        int r = idx - 131072;
        int dir = r / 311296;
        int o = r % 311296;
        const float* Wg0 = dir ? bWg0 : fWg0;
        const float* Wgr = dir ? bWgr : fWgr;
        const float* Wo0 = dir ? bWo0 : fWo0;
        const float* Wor = dir ? bWor : fWor;
        if (o < 16384) {
            int n = o >> 7, k = o & 127;
            val = Wg0[k * 128 + n];
        } else if (o < 147456) {
            int p = o - 16384;
            int j = p >> 16, q = p & 65535;
            int n = q >> 8, k = q & 255;
            val = Wgr[j * 65536 + k * 256 + n];
        } else if (o < 180224) {
            int p = o - 147456;
            int s = p >> 14, q = p & 16383;
            int n = q >> 7, k = q & 127;
            val = Wo0[s * 16384 + k * 128 + n];
        } else {
            int p = o - 180224;
            int js = p >> 15, q = p & 32767;
            int n = q >> 8, k = q & 255;
            val = Wor[js * 32768 + k * 128 + n];
        }
    } else if (idx < 819200) {
        val = sfWih[idx - 753664];
    } else {
        val = sbWih[idx - 819200];
    }
    dst[idx] = f2bf(val);
}

__global__ __launch_bounds__(256) void tokrev_k(const int* __restrict__ idx,
                                                const int* __restrict__ lens,
                                                int* __restrict__ tokrev)
{
    int t = blockIdx.x * 256 + threadIdx.x;
    if (t >= BB * LL) return;
    int b = t / LL, tt = t % LL;
    int r = lens[b] - 1 - tt;
    r = r < 0 ? 0 : (r > LL - 1 ? LL - 1 : r);
    tokrev[t] = idx[b * LL + r];
}

// ---------------- bf16 MFMA GEMM ----------------
// AMODE 0: A[m*lda+k]; 1: embed_bf[gidx[m*gs+go]*128+k]; 2: k<128 embed else H2[m*128+k-128]
// EP 0: none; 1: relu; 2: sigmoid(v)*aux_bf16[m*ldaux+n]
// OF32 1: out f32, 0: out bf16
template<int AMODE, int EP, int OF32>
__global__ __launch_bounds__(256) void hgemm_k(
    const unsigned short* __restrict__ A, int lda,
    const int* __restrict__ gidx, int gstride, int goff,
    const unsigned short* __restrict__ H2,
    const unsigned short* __restrict__ Wt,   // [N][K] bf16
    const float* __restrict__ bias,
    const unsigned short* __restrict__ aux, int ldaux,
    void* __restrict__ outp, int ldo, int ocol,
    int M, int N, int K)
{
    __shared__ unsigned short Asm[128 * 64];
    __shared__ unsigned short Bsm[128 * 64];
    const int tid = threadIdx.x;
    const int lane = tid & 63, w = tid >> 6;
    const int wm = w >> 1, wn = w & 1;
    const int bm0 = blockIdx.x * 128, bn0 = blockIdx.y * 128;
    f32x4 acc[4][4];
#pragma unroll
    for (int i = 0; i < 4; ++i)
#pragma unroll
        for (int j = 0; j < 4; ++j) acc[i][j] = (f32x4){0.f, 0.f, 0.f, 0.f};

    for (int kt = 0; kt < K; kt += 64) {
#pragma unroll
        for (int r = 0; r < 4; ++r) {
            int id = tid + r * 256;
            int row = id >> 3, cc = id & 7;
            int m = bm0 + row;
            s16x8 v = {0, 0, 0, 0, 0, 0, 0, 0};
            if (m < M) {
                const unsigned short* src;
                if (AMODE == 0) {
                    src = A + (size_t)m * lda + kt + cc * 8;
                } else if (AMODE == 1) {
                    int g = gidx[m * gstride + goff];
                    src = A + (size_t)g * 128 + kt + cc * 8;
                } else {
                    int k0 = kt + cc * 8;
                    if (k0 < 128) {
                        int g = gidx[m * gstride + goff];
                        src = A + (size_t)g * 128 + k0;
                    } else {
                        src = H2 + (size_t)m * 128 + (k0 - 128);
                    }
                }
                v = *(const s16x8*)src;
            }
            int byt = (cc * 16) ^ ((row & 7) << 4);
            *(s16x8*)((char*)Asm + row * 128 + byt) = v;
        }
#pragma unroll
        for (int r = 0; r < 4; ++r) {
            int id = tid + r * 256;
            int row = id >> 3, cc = id & 7;
            s16x8 v = *(const s16x8*)(Wt + (size_t)(bn0 + row) * K + kt + cc * 8);
            int byt = (cc * 16) ^ ((row & 7) << 4);
            *(s16x8*)((char*)Bsm + row * 128 + byt) = v;
        }
        __syncthreads();
#pragma unroll
        for (int ks = 0; ks < 2; ++ks) {
            s16x8 af[4], bf[4];
#pragma unroll
            for (int mi = 0; mi < 4; ++mi) {
                int row = wm * 64 + mi * 16 + (lane & 15);
                int byt = (ks * 64 + ((lane >> 4) * 16)) ^ ((row & 7) << 4);
                af[mi] = *(const s16x8*)((char*)Asm + row * 128 + byt);
            }
#pragma unroll
            for (int ni = 0; ni < 4; ++ni) {
                int row = wn * 64 + ni * 16 + (lane & 15);
                int byt = (ks * 64 + ((lane >> 4) * 16)) ^ ((row & 7) << 4);
                bf[ni] = *(const s16x8*)((char*)Bsm + row * 128 + byt);
            }
#pragma unroll
            for (int mi = 0; mi < 4; ++mi)
#pragma unroll
                for (int ni = 0; ni < 4; ++ni)
                    acc[mi][ni] = __builtin_amdgcn_mfma_f32_16x16x32_bf16(af[mi], bf[ni], acc[mi][ni], 0, 0, 0);
        }
        __syncthreads();
    }
#pragma unroll
    for (int mi = 0; mi < 4; ++mi) {
#pragma unroll
        for (int ni = 0; ni < 4; ++ni) {
            int n = bn0 + wn * 64 + ni * 16 + (lane & 15);
#pragma unroll
            for (int j = 0; j < 4; ++j) {
                int m = bm0 + wm * 64 + mi * 16 + (lane >> 4) * 4 + j;
                if (m < M) {
                    float v = acc[mi][ni][j] + bias[n];
                    if (EP == 1) v = fmaxf(v, 0.f);
                    if (EP == 2) v = sigm(v) * bf2f(aux[(size_t)m * ldaux + n]);
                    if (OF32) ((float*)outp)[(size_t)m * ldo + ocol + n] = v;
                    else ((unsigned short*)outp)[(size_t)m * ldo + ocol + n] = f2bf(v);
                }
            }
        }
    }
}

// ---------------- node LSTM cell ----------------
__global__ __launch_bounds__(256) void lstm_cell_k(const float* __restrict__ G,
                                                   unsigned short* __restrict__ hb,
                                                   float* __restrict__ c, int M)
{
    int i = blockIdx.x * 256 + threadIdx.x;
    if (i >= M * HH) return;
    int m = i >> 7, j = i & 127;
    const float* g = G + (size_t)m * 512;
    float i_ = g[j], f_ = g[128 + j], gg = g[256 + j], o_ = g[384 + j];
    float cc = c[i];
    cc = sigm(f_) * cc + sigm(i_) * tanhf(gg);
    float hh = sigm(o_) * tanhf(cc);
    c[i] = cc;
    hb[i] = f2bf(hh);
}

// ---------------- per-sequence LSTM recurrence ----------------
__global__ __launch_bounds__(512) void seq_lstm_k(const float* __restrict__ xgf,
                                                  const float* __restrict__ xgb,
                                                  const float* __restrict__ wt_all,
                                                  const int* __restrict__ lens,
                                                  float* __restrict__ senc)
{
    int bid = blockIdx.x;
    int dir = bid >= BB ? 1 : 0;
    int b = dir ? bid - BB : bid;
    int len = lens[b];
    const float* xg = (dir ? xgb : xgf) + (size_t)b * LL * 512;
    const float* wT = wt_all + (size_t)(dir ? 3 : 1) * 65536;
    int tid = threadIdx.x;
    int gate = tid >> 7;
    float wreg[128];
#pragma unroll
    for (int k = 0; k < 128; ++k) wreg[k] = wT[k * 512 + tid];
    __shared__ __align__(16) float hsh[128];
    __shared__ __align__(16) float gsh[512];
    float cj = 0.f;
    if (tid < 128) hsh[tid] = 0.f;
    __syncthreads();
    float xcur = xg[tid];
    for (int t = 0; t < len; ++t) {
        float xnext = (t + 1 < len) ? xg[(size_t)(t + 1) * 512 + tid] : 0.f;
        // 4 independent accumulator chains (dep depth 32 instead of 128)
        float p0 = 0.f, p1 = 0.f, p2 = 0.f, p3 = 0.f;
#pragma unroll
        for (int k16 = 0; k16 < 8; ++k16) {
            float4 h0 = *(const float4*)&hsh[k16 * 16 + 0];
            float4 h1 = *(const float4*)&hsh[k16 * 16 + 4];
            float4 h2 = *(const float4*)&hsh[k16 * 16 + 8];
            float4 h3 = *(const float4*)&hsh[k16 * 16 + 12];
            const float* wb_ = wreg + k16 * 16;
            p0 += h0.x * wb_[0] + h0.y * wb_[1] + h0.z * wb_[2] + h0.w * wb_[3];
            p1 += h1.x * wb_[4] + h1.y * wb_[5] + h1.z * wb_[6] + h1.w * wb_[7];
            p2 += h2.x * wb_[8] + h2.y * wb_[9] + h2.z * wb_[10] + h2.w * wb_[11];
            p3 += h3.x * wb_[12] + h3.y * wb_[13] + h3.z * wb_[14] + h3.w * wb_[15];
        }
        float acc = xcur + ((p0 + p1) + (p2 + p3));
        float tv = (gate == 2) ? tanhf(acc) : sigm(acc);
        gsh[tid] = tv;
        __syncthreads();
        if (tid < 128) {
            float i_ = gsh[tid], f_ = gsh[128 + tid], g_ = gsh[256 + tid], o_ = gsh[384 + tid];
            cj = f_ * cj + i_ * g_;
            float hv2 = o_ * tanhf(cj);
            hsh[tid] = hv2;
            int tout = dir ? (len - 1 - t) : t;
            senc[((size_t)b * LL + tout) * 256 + dir * 128 + tid] = hv2;
        }
        __syncthreads();
        xcur = xnext;
    }
}

// ---------------- mask + zero-invalid + max_len ----------------
__global__ __launch_bounds__(256) void finalize_k(const int* __restrict__ idx,
                                                  const int* __restrict__ lens,
                                                  float* __restrict__ senc,
                                                  float* __restrict__ mask,
                                                  float* __restrict__ omax,
                                                  const int* __restrict__ mlin)
{
    int t = blockIdx.x * 256 + threadIdx.x;
    if (t == 0) omax[0] = (float)mlin[0];
    if (t >= BB * LL) return;
    int b = t / LL, tt = t % LL;
    mask[t] = (idx[t] == 0) ? 1.f : 0.f;
    if (tt >= lens[b]) {
        float* row = senc + (size_t)t * 256;
        for (int j = 0; j < 256; ++j) row[j] = 0.f;
    }
}

// ---------------- gated-attention context (bf16 in, bf16 out) ----------------
template<int D>
__global__ __launch_bounds__(256) void attn_ctx_k(const unsigned short* __restrict__ hid,
                                                  const int* __restrict__ adj,
                                                  const float* __restrict__ att0,
                                                  const float* __restrict__ att1,
                                                  unsigned short* __restrict__ ctx)
{
    constexpr int V = D / 64;
    int lane = threadIdx.x & 63, wid = threadIdx.x >> 6;
    int n = blockIdx.x * 4 + wid;
    if (n >= NN) return;
    float a0[V], a1[V], sv[V];
#pragma unroll
    for (int j = 0; j < V; ++j) {
        a0[j] = att0[lane * V + j];
        a1[j] = att1[lane * V + j];
    }
    {
        if (V == 2) {
            unsigned int u = *(const unsigned int*)(hid + (size_t)n * D + lane * 2);
            sv[0] = bf2f(u); sv[1] = bf2f(u >> 16);
        } else {
            uint2 u = *(const uint2*)(hid + (size_t)n * D + lane * 4);
            sv[0] = bf2f(u.x); sv[1] = bf2f(u.x >> 16);
            sv[2] = bf2f(u.y); sv[3] = bf2f(u.y >> 16);
        }
    }
    float p = 0.f;
#pragma unroll
    for (int j = 0; j < V; ++j) p += sv[j] * a0[j];
#pragma unroll
    for (int m = 1; m < 64; m <<= 1) p += __shfl_xor(p, m);
    float s_self = p;
    float nv[KNB][V];
    float sc[KNB];
#pragma unroll
    for (int k = 0; k < KNB; ++k) {
        int nb = adj[n * KNB + k];
        float q = 0.f;
        if (nb < NN) {
            if (V == 2) {
                unsigned int u = *(const unsigned int*)(hid + (size_t)nb * D + lane * 2);
                nv[k][0] = bf2f(u); nv[k][1] = bf2f(u >> 16);
            } else {
                uint2 u = *(const uint2*)(hid + (size_t)nb * D + lane * 4);
                nv[k][0] = bf2f(u.x); nv[k][1] = bf2f(u.x >> 16);
                nv[k][2] = bf2f(u.y); nv[k][3] = bf2f(u.y >> 16);
            }
        } else {
#pragma unroll
            for (int j = 0; j < V; ++j) nv[k][j] = 0.f;
        }
#pragma unroll
        for (int j = 0; j < V; ++j) q += nv[k][j] * a1[j];
#pragma unroll
        for (int m = 1; m < 64; m <<= 1) q += __shfl_xor(q, m);
        sc[k] = s_self + q;
    }
    float mx = sc[0];
#pragma unroll
    for (int k = 1; k < KNB; ++k) mx = fmaxf(mx, sc[k]);
    float s = 0.f;
#pragma unroll
    for (int k = 0; k < KNB; ++k) { sc[k] = expf(sc[k] - mx); s += sc[k]; }
    float inv = 1.f / s;
#pragma unroll
    for (int j2 = 0; j2 < V; j2 += 2) {
        float c0 = 0.f, c1 = 0.f;
#pragma unroll
        for (int k = 0; k < KNB; ++k) { c0 += sc[k] * nv[k][j2]; c1 += sc[k] * nv[k][j2 + 1]; }
        unsigned int pk = (unsigned int)f2bf(c0 * inv) | ((unsigned int)f2bf(c1 * inv) << 16);
        *(unsigned int*)(ctx + (size_t)n * D + lane * V + j2) = pk;
    }
}

// ---------------- graph max pool: two-stage ----------------
__global__ __launch_bounds__(512) void gmax1_k(const float* __restrict__ gh, float* __restrict__ part)
{
    int g = blockIdx.x, ch = blockIdx.y;
    int c = threadIdx.x;
    const float* p = gh + ((size_t)g * 1000 + ch * (1000 / GCH)) * 512 + c;
    float m = -1e30f;
#pragma unroll 5
    for (int i = 0; i < 1000 / GCH; ++i) m = fmaxf(m, p[(size_t)i * 512]);
    part[((size_t)g * GCH + ch) * 512 + c] = m;
}

__global__ __launch_bounds__(512) void gmax2_k(const float* __restrict__ part, float* __restrict__ ge)
{
    int g = blockIdx.x;
    int c = threadIdx.x;
    float m = -1e30f;
#pragma unroll
    for (int i = 0; i < GCH; ++i) m = fmaxf(m, part[((size_t)g * GCH + i) * 512 + c]);
    ge[g * 512 + c] = m;
}

extern "C" void kernel_launch(void* const* d_in, const int* in_sizes, int n_in,
                              void* d_out, int out_size, void* d_ws, size_t ws_size,
                              hipStream_t stream)
{
    const float* embed = (const float*)d_in[0];
    const float* sfWih = (const float*)d_in[1];
    const float* sfWhh = (const float*)d_in[2];
    const float* sfb   = (const float*)d_in[3];
    const float* sbWih = (const float*)d_in[4];
    const float* sbWhh = (const float*)d_in[5];
    const float* sbb   = (const float*)d_in[6];
    const float* ndWih = (const float*)d_in[7];
    const float* ndWhh = (const float*)d_in[8];
    const float* ndb   = (const float*)d_in[9];
    const int* nodefeat = (const int*)d_in[30];
    const int* adjs[2]  = {(const int*)d_in[31], (const int*)d_in[32]};
    const int* idxseq   = (const int*)d_in[33];
    const int* lens     = (const int*)d_in[34];
    const int* mlin     = (const int*)d_in[35];

    // ---- workspace layout (f32 units), phase-aliased ----
    float* ws   = (float*)d_ws;
    float* wt   = ws;                         // 262,144 : 4 seq weights f32 transposed
    float* P1   = ws + 262144;                // 6,560,000
    float* xgf  = P1;
    float* xgb  = P1 + 3276800;
    int*   tokrev = (int*)(P1 + 6553600);
    float* cn   = P1;                         // phase 2 cell state (3,200,000)
    unsigned short* HA = (unsigned short*)P1;               // phase 3
    unsigned short* HB = (unsigned short*)(P1 + 3200000);
    unsigned short* embedbf = (unsigned short*)(ws + 6822144);   // 4,096,000 us
    unsigned short* warena  = (unsigned short*)(ws + 8870144);   // 884,736 us
    unsigned short* hbf     = (unsigned short*)(ws + 9312512);   // 3,200,000 us
    float* G    = ws + 10912512;              // 12,800,000
    unsigned short* ctxb  = (unsigned short*)G;
    unsigned short* gctxb = (unsigned short*)(G + 3200000);
    float* gmaxp = G;                         // phase 4 partials (256,000 f32), G is dead by then

    float* outf  = (float*)d_out;
    float* gh    = outf;                 // 12,800,000
    float* ge    = outf + 12800000;      // 12,800
    float* omax  = outf + 12812800;      // 1
    float* senc  = outf + 12812801;      // 1,638,400
    float* omask = outf + 14451201;      // 6,400

    // phase 0: preps
    transpose4_k<<<dim3(1024), dim3(256), 0, stream>>>(sfWih, sfWhh, sbWih, sbWhh, wt);
    tokrev_k<<<dim3((BB * LL + 255) / 256), dim3(256), 0, stream>>>(idxseq, lens, tokrev);
    embconv_k<<<dim3(VV * 128 / 256), dim3(256), 0, stream>>>(embed, embedbf);
    wprep_k<<<dim3(3456), dim3(256), 0, stream>>>(ndWih, ndWhh,
        (const float*)d_in[12], (const float*)d_in[14], (const float*)d_in[16], (const float*)d_in[18],
        (const float*)d_in[22], (const float*)d_in[24], (const float*)d_in[26], (const float*)d_in[28],
        sfWih, sbWih, warena);

    // phase 1: sequence bi-LSTM (xg via bf16 MFMA, recurrence f32)
    hgemm_k<1, 0, 1><<<dim3(50, 4), dim3(256), 0, stream>>>(embedbf, 0, idxseq, 1, 0, nullptr,
        warena + 753664, sfb, nullptr, 0, xgf, 512, 0, BB * LL, 512, 128);
    hgemm_k<1, 0, 1><<<dim3(50, 4), dim3(256), 0, stream>>>(embedbf, 0, tokrev, 1, 0, nullptr,
        warena + 819200, sbb, nullptr, 0, xgb, 512, 0, BB * LL, 512, 128);
    seq_lstm_k<<<dim3(2 * BB), dim3(512), 0, stream>>>(xgf, xgb, wt, lens, senc);
    finalize_k<<<dim3((BB * LL + 255) / 256), dim3(256), 0, stream>>>(idxseq, lens, senc, omask, omax, mlin);

    // phase 2: node LSTM (4 steps)
    zero_k<<<dim3((3200000 + 255) / 256), dim3(256), 0, stream>>>(cn, 3200000);
    zero_k<<<dim3((1600000 + 255) / 256), dim3(256), 0, stream>>>((float*)hbf, 1600000);
    for (int t = 0; t < NTK; ++t) {
        hgemm_k<2, 0, 1><<<dim3(196, 4), dim3(256), 0, stream>>>(embedbf, 0, nodefeat, NTK, t, hbf,
            warena, ndb, nullptr, 0, G, 512, 0, NN, 512, 256);
        lstm_cell_k<<<dim3(NN * HH / 256), dim3(256), 0, stream>>>(G, hbf, cn, NN);
    }

    // phase 3: graph attention layers
    for (int dir = 0; dir < 2; ++dir) {
        int base = 10 + dir * 10;
        const float* att0w = (const float*)d_in[base + 0];
        const float* attrw = (const float*)d_in[base + 1];
        const float* bg0   = (const float*)d_in[base + 3];
        const float* bgr   = (const float*)d_in[base + 5];
        const float* bo0   = (const float*)d_in[base + 7];
        const float* bor   = (const float*)d_in[base + 9];
        const int* adj = adjs[dir];
        const unsigned short* wb = warena + 131072 + dir * 311296;
        for (int l = 0; l < 3; ++l) {
            int D = (l == 0) ? 128 : 256;
            int j = l - 1;
            const unsigned short* cur = (l == 0) ? hbf : (l == 1 ? HA : HB);
            const float* a0 = (l == 0) ? att0w : attrw + (size_t)j * 512;
            const float* a1 = (l == 0) ? att0w + 128 : attrw + (size_t)j * 512 + 256;
            const unsigned short* wg  = (l == 0) ? wb : wb + 16384 + j * 65536;
            const unsigned short* wos = (l == 0) ? wb + 147456 : wb + 180224 + (j * 2 + 0) * 32768;
            const unsigned short* won = (l == 0) ? wb + 163840 : wb + 180224 + (j * 2 + 1) * 32768;
            const float* bg = (l == 0) ? bg0 : bgr + (size_t)j * 256;
            const float* bos = (l == 0) ? bo0 : bor + (size_t)j * 256;
            const float* bon = (l == 0) ? bo0 + 128 : bor + (size_t)j * 256 + 128;

            if (D == 128)
                attn_ctx_k<128><<<dim3(NN / 4), dim3(256), 0, stream>>>(cur, adj, a0, a1, ctxb);
            else
                attn_ctx_k<256><<<dim3(NN / 4), dim3(256), 0, stream>>>(cur, adj, a0, a1, ctxb);

            hgemm_k<0, 2, 0><<<dim3(196, D / 128), dim3(256), 0, stream>>>(cur, D, nullptr, 0, 0, nullptr,
                wg, bg, ctxb, D, gctxb, D, 0, NN, D, D);

            if (l == 2) {
                hgemm_k<0, 1, 1><<<dim3(196, 1), dim3(256), 0, stream>>>(cur, D, nullptr, 0, 0, nullptr,
                    wos, bos, nullptr, 0, gh, 512, dir * 256, NN, 128, D);
                hgemm_k<0, 1, 1><<<dim3(196, 1), dim3(256), 0, stream>>>(gctxb, D, nullptr, 0, 0, nullptr,
                    won, bon, nullptr, 0, gh, 512, dir * 256 + 128, NN, 128, D);
            } else {
                unsigned short* ob = (l == 0) ? HA : HB;
                hgemm_k<0, 1, 0><<<dim3(196, 1), dim3(256), 0, stream>>>(cur, D, nullptr, 0, 0, nullptr,
                    wos, bos, nullptr, 0, ob, 256, 0, NN, 128, D);
                hgemm_k<0, 1, 0><<<dim3(196, 1), dim3(256), 0, stream>>>(gctxb, D, nullptr, 0, 0, nullptr,
                    won, bon, nullptr, 0, ob, 256, 128, NN, 128, D);
            }
        }
    }

    // phase 4: graph embedding max-pool (two-stage)
    gmax1_k<<<dim3(NGRAPH, GCH), dim3(512), 0, stream>>>(gh, gmaxp);
    gmax2_k<<<dim3(NGRAPH), dim3(512), 0, stream>>>(gmaxp, ge);
}

// Round 4
// 1171.851 us; speedup vs baseline: 1.7540x; 1.0079x over previous
//
#include <hip/hip_runtime.h>
#include <math.h>

#define NN 25000
#define KNB 16
#define HH 128
#define VV 32000
#define BB 50
#define LL 128
#define NTK 4
#define NGRAPH 25
#define GCH 20

typedef __attribute__((ext_vector_type(8))) short s16x8;
typedef __attribute__((ext_vector_type(4))) float f32x4;

__device__ __forceinline__ float fexp2(float x) {
#if __has_builtin(__builtin_amdgcn_exp2f)
    return __builtin_amdgcn_exp2f(x);
#else
    return exp2f(x);
#endif
}
__device__ __forceinline__ float frcp(float x) {
#if __has_builtin(__builtin_amdgcn_rcpf)
    return __builtin_amdgcn_rcpf(x);
#else
    return 1.f / x;
#endif
}
__device__ __forceinline__ float fsigm(float x) { return frcp(1.f + fexp2(x * -1.4426950408889634f)); }
__device__ __forceinline__ float ftanh(float x) { return 1.f - 2.f * frcp(1.f + fexp2(x * 2.8853900817779268f)); }

__device__ __forceinline__ unsigned short f2bf(float x) {
    unsigned int u = __float_as_uint(x);
    unsigned int r = (u + 0x7fffu + ((u >> 16) & 1u)) >> 16;
    return (unsigned short)r;
}
__device__ __forceinline__ float bf2f(unsigned int b) {
    return __uint_as_float((b & 0xffffu) << 16);
}

// ---------------- transpose 2 seq Whh (512,128)->(128,512), gate-interleaved cols ----------------
__global__ __launch_bounds__(256) void transpose2_k(
    const float* __restrict__ s0, const float* __restrict__ s1,
    float* __restrict__ dst)
{
    int t = blockIdx.x * 256 + threadIdx.x;
    if (t >= 2 * 65536) return;
    int mat = t >> 16, r = t & 65535;
    int k = r >> 9, g = r & 511;
    const float* s = mat ? s1 : s0;
    int col = ((g & 127) << 2) | (g >> 7);   // unit*4+gate
    dst[mat * 65536 + k * 512 + col] = s[g * 128 + k];
}

__global__ __launch_bounds__(256) void zero_k(float* __restrict__ p, int n)
{
    int i = blockIdx.x * 256 + threadIdx.x;
    if (i < n) p[i] = 0.f;
}

// ---------------- embed f32 -> bf16 ----------------
__global__ __launch_bounds__(256) void embconv_k(const float* __restrict__ e,
                                                 unsigned short* __restrict__ o)
{
    int i = blockIdx.x * 256 + threadIdx.x;
    if (i < VV * 128) o[i] = f2bf(e[i]);
}

// ---------------- weight prep: convert+transpose weights to bf16 [N][K] ----------------
// arena layout (ushort elems):
//   nodeWt [512][256] @ 0, row r = unit*4+gate (gate-interleaved), cols = [Wih | Whh]
//   per dir wb = 131072 + dir*311296:
//     wg0t  [128][128] @ wb+0
//     wgrt  [256][256] @ wb+16384 + j*65536   (j=0,1)
//     wo0st [128][128] @ wb+147456 ; wo0nt @ wb+163840
//     wort  [128][256] @ wb+180224 + (j*2+s)*32768
//   sfWih bf16 [512][128] @ 753664 ; sbWih @ 819200   (total 884736)
__global__ __launch_bounds__(256) void wprep_k(
    const float* __restrict__ ndWih, const float* __restrict__ ndWhh,
    const float* __restrict__ fWg0, const float* __restrict__ fWgr,
    const float* __restrict__ fWo0, const float* __restrict__ fWor,
    const float* __restrict__ bWg0, const float* __restrict__ bWgr,
    const float* __restrict__ bWo0, const float* __restrict__ bWor,
    const float* __restrict__ sfWih, const float* __restrict__ sbWih,
    unsigned short* __restrict__ dst)
{
    int idx = blockIdx.x * 256 + threadIdx.x;
    if (idx >= 884736) return;
    float val;
    if (idx < 131072) {
        int r = idx >> 8, k = idx & 255;
        int unit = r >> 2, gate = r & 3;
        int srow = (gate << 7) + unit;
        val = (k < 128) ? ndWih[srow * 128 + k] : ndWhh[srow * 128 + (k - 128)];
    } else if (idx < 753664) {
        int r = idx - 131072;
        int dir = r / 311296;
        int o = r % 311296;
        const float* Wg0 = dir ? bWg0 : fWg0;
        const float* Wgr = dir ? bWgr : fWgr;
        const float* Wo0 = dir ? bWo0 : fWo0;
        const float* Wor = dir ? bWor : fWor;
        if (o < 16384) {
            int n = o >> 7, k = o & 127;
            val = Wg0[k * 128 + n];
        } else if (o < 147456) {
            int p = o - 16384;
            int j = p >> 16, q = p & 65535;
            int n = q >> 8, k = q & 255;
            val = Wgr[j * 65536 + k * 256 + n];
        } else if (o < 180224) {
            int p = o - 147456;
            int s = p >> 14, q = p & 16383;
            int n = q >> 7, k = q & 127;
            val = Wo0[s * 16384 + k * 128 + n];
        } else {
            int p = o - 180224;
            int js = p >> 15, q = p & 32767;
            int n = q >> 8, k = q & 255;
            val = Wor[js * 32768 + k * 128 + n];
        }
    } else if (idx < 819200) {
        val = sfWih[idx - 753664];
    } else {
        val = sbWih[idx - 819200];
    }
    dst[idx] = f2bf(val);
}

__global__ __launch_bounds__(256) void tokrev_k(const int* __restrict__ idx,
                                                const int* __restrict__ lens,
                                                int* __restrict__ tokrev)
{
    int t = blockIdx.x * 256 + threadIdx.x;
    if (t >= BB * LL) return;
    int b = t / LL, tt = t % LL;
    int r = lens[b] - 1 - tt;
    r = r < 0 ? 0 : (r > LL - 1 ? LL - 1 : r);
    tokrev[t] = idx[b * LL + r];
}

// ---------------- bf16 MFMA GEMM ----------------
// AMODE 0: A[m*lda+k]; 1: embed_bf[gidx[m*gs+go]*128+k]; 2: k<128 embed else H2[m*128+k-128]
// EP 0: none; 1: relu; 2: sigmoid(v)*aux_bf16[m*ldaux+n]; 3: fused LSTM cell (gate-interleaved N)
// OF32 1: out f32, 0: out bf16 ; PERM 1: permute out col n -> unit*4+gate (f32 path)
template<int AMODE, int EP, int OF32, int PERM>
__global__ __launch_bounds__(256) void hgemm_k(
    const unsigned short* __restrict__ A, int lda,
    const int* __restrict__ gidx, int gstride, int goff,
    const unsigned short* __restrict__ H2,
    const unsigned short* __restrict__ Wt,   // [N][K] bf16
    const float* __restrict__ bias,
    const unsigned short* __restrict__ aux, int ldaux,
    void* __restrict__ outp, int ldo, int ocol,
    int M, int N, int K, float* __restrict__ cbuf)
{
    __shared__ unsigned short Asm[128 * 64];
    __shared__ unsigned short Bsm[128 * 64];
    const int tid = threadIdx.x;
    const int lane = tid & 63, w = tid >> 6;
    const int wm = w >> 1, wn = w & 1;
    const int bm0 = blockIdx.x * 128, bn0 = blockIdx.y * 128;
    f32x4 acc[4][4];
#pragma unroll
    for (int i = 0; i < 4; ++i)
#pragma unroll
        for (int j = 0; j < 4; ++j) acc[i][j] = (f32x4){0.f, 0.f, 0.f, 0.f};

    for (int kt = 0; kt < K; kt += 64) {
#pragma unroll
        for (int r = 0; r < 4; ++r) {
            int id = tid + r * 256;
            int row = id >> 3, cc = id & 7;
            int m = bm0 + row;
            s16x8 v = {0, 0, 0, 0, 0, 0, 0, 0};
            if (m < M) {
                const unsigned short* src;
                if (AMODE == 0) {
                    src = A + (size_t)m * lda + kt + cc * 8;
                } else if (AMODE == 1) {
                    int g = gidx[m * gstride + goff];
                    src = A + (size_t)g * 128 + kt + cc * 8;
                } else {
                    int k0 = kt + cc * 8;
                    if (k0 < 128) {
                        int g = gidx[m * gstride + goff];
                        src = A + (size_t)g * 128 + k0;
                    } else {
                        src = H2 + (size_t)m * 128 + (k0 - 128);
                    }
                }
                v = *(const s16x8*)src;
            }
            int byt = (cc * 16) ^ ((row & 7) << 4);
            *(s16x8*)((char*)Asm + row * 128 + byt) = v;
        }
#pragma unroll
        for (int r = 0; r < 4; ++r) {
            int id = tid + r * 256;
            int row = id >> 3, cc = id & 7;
            s16x8 v = *(const s16x8*)(Wt + (size_t)(bn0 + row) * K + kt + cc * 8);
            int byt = (cc * 16) ^ ((row & 7) << 4);
            *(s16x8*)((char*)Bsm + row * 128 + byt) = v;
        }
        __syncthreads();
#pragma unroll
        for (int ks = 0; ks < 2; ++ks) {
            s16x8 af[4], bf[4];
#pragma unroll
            for (int mi = 0; mi < 4; ++mi) {
                int row = wm * 64 + mi * 16 + (lane & 15);
                int byt = (ks * 64 + ((lane >> 4) * 16)) ^ ((row & 7) << 4);
                af[mi] = *(const s16x8*)((char*)Asm + row * 128 + byt);
            }
#pragma unroll
            for (int ni = 0; ni < 4; ++ni) {
                int row = wn * 64 + ni * 16 + (lane & 15);
                int byt = (ks * 64 + ((lane >> 4) * 16)) ^ ((row & 7) << 4);
                bf[ni] = *(const s16x8*)((char*)Bsm + row * 128 + byt);
            }
#pragma unroll
            for (int mi = 0; mi < 4; ++mi)
#pragma unroll
                for (int ni = 0; ni < 4; ++ni)
                    acc[mi][ni] = __builtin_amdgcn_mfma_f32_16x16x32_bf16(af[mi], bf[ni], acc[mi][ni], 0, 0, 0);
        }
        __syncthreads();
    }
    if (EP == 3) {
        // fused LSTM cell: N gate-interleaved (unit = n>>2, gate = n&3)
#pragma unroll
        for (int mi = 0; mi < 4; ++mi) {
#pragma unroll
            for (int ni = 0; ni < 4; ++ni) {
                int n = bn0 + wn * 64 + ni * 16 + (lane & 15);
                int unit = n >> 2, gate = n & 3;
                float bval = bias[(gate << 7) + unit];
#pragma unroll
                for (int j = 0; j < 4; ++j) {
                    int m = bm0 + wm * 64 + mi * 16 + (lane >> 4) * 4 + j;
                    float v = acc[mi][ni][j] + bval;
                    float tv = (gate == 2) ? ftanh(v) : fsigm(v);
                    float v1 = __shfl_xor(tv, 1), v2 = __shfl_xor(tv, 2), v3 = __shfl_xor(tv, 3);
                    if (gate == 0 && m < M) {
                        // slots at gate0 lane: i=tv, f=v1, g=v2, o=v3 (post-nonlinearity)
                        float cc = cbuf[(size_t)m * HH + unit];
                        cc = v1 * cc + tv * v2;
                        cbuf[(size_t)m * HH + unit] = cc;
                        ((unsigned short*)outp)[(size_t)m * HH + unit] = f2bf(v3 * ftanh(cc));
                    }
                }
            }
        }
    } else {
#pragma unroll
        for (int mi = 0; mi < 4; ++mi) {
#pragma unroll
            for (int ni = 0; ni < 4; ++ni) {
                int n = bn0 + wn * 64 + ni * 16 + (lane & 15);
#pragma unroll
                for (int j = 0; j < 4; ++j) {
                    int m = bm0 + wm * 64 + mi * 16 + (lane >> 4) * 4 + j;
                    if (m < M) {
                        float v = acc[mi][ni][j] + bias[n];
                        if (EP == 1) v = fmaxf(v, 0.f);
                        if (EP == 2) v = fsigm(v) * bf2f(aux[(size_t)m * ldaux + n]);
                        int nn = PERM ? (((n & 127) << 2) | (n >> 7)) : n;
                        if (OF32) ((float*)outp)[(size_t)m * ldo + ocol + nn] = v;
                        else ((unsigned short*)outp)[(size_t)m * ldo + ocol + nn] = f2bf(v);
                    }
                }
            }
        }
    }
}

// ---------------- per-sequence LSTM recurrence (gate-interleaved, 1 barrier/step) ----------------
__global__ __launch_bounds__(512, 2) void seq_lstm_k(const float* __restrict__ xgf,
                                                     const float* __restrict__ xgb,
                                                     const float* __restrict__ wt_all,
                                                     const int* __restrict__ lens,
                                                     float* __restrict__ senc)
{
    int bid = blockIdx.x;
    int dir = bid >= BB ? 1 : 0;
    int b = dir ? bid - BB : bid;
    int len = lens[b];
    const float* xg = (dir ? xgb : xgf) + (size_t)b * LL * 512;
    const float* wT = wt_all + (size_t)dir * 65536;
    int tid = threadIdx.x;
    int q = tid & 3, unit = tid >> 2;
    float wreg[128];
#pragma unroll
    for (int k = 0; k < 128; ++k) wreg[k] = wT[k * 512 + tid];
    __shared__ __align__(16) float hsh[2][128];
    float cj = 0.f;
    if (tid < 128) hsh[0][tid] = 0.f;
    __syncthreads();
    float xcur = xg[tid];
    int pb = 0;
    for (int t = 0; t < len; ++t) {
        float xnext = (t + 1 < len) ? xg[(size_t)(t + 1) * 512 + tid] : 0.f;
        const float* h = hsh[pb];
        float p0 = 0.f, p1 = 0.f, p2 = 0.f, p3 = 0.f;
#pragma unroll
        for (int k16 = 0; k16 < 8; ++k16) {
            float4 h0 = *(const float4*)&h[k16 * 16 + 0];
            float4 h1 = *(const float4*)&h[k16 * 16 + 4];
            float4 h2 = *(const float4*)&h[k16 * 16 + 8];
            float4 h3 = *(const float4*)&h[k16 * 16 + 12];
            const float* wb_ = wreg + k16 * 16;
            p0 += h0.x * wb_[0] + h0.y * wb_[1] + h0.z * wb_[2] + h0.w * wb_[3];
            p1 += h1.x * wb_[4] + h1.y * wb_[5] + h1.z * wb_[6] + h1.w * wb_[7];
            p2 += h2.x * wb_[8] + h2.y * wb_[9] + h2.z * wb_[10] + h2.w * wb_[11];
            p3 += h3.x * wb_[12] + h3.y * wb_[13] + h3.z * wb_[14] + h3.w * wb_[15];
        }
        float accv = xcur + ((p0 + p1) + (p2 + p3));
        float tv = (q == 2) ? ftanh(accv) : fsigm(accv);
        float v1 = __shfl_xor(tv, 1), v2 = __shfl_xor(tv, 2), v3 = __shfl_xor(tv, 3);
        if (q == 0) {
            cj = v1 * cj + tv * v2;           // f*c + i*g
            float hv = v3 * ftanh(cj);        // o*tanh(c)
            hsh[pb ^ 1][unit] = hv;
            int tout = dir ? (len - 1 - t) : t;
            senc[((size_t)b * LL + tout) * 256 + dir * 128 + unit] = hv;
        }
        __syncthreads();
        pb ^= 1;
        xcur = xnext;
    }
}

// ---------------- mask + zero-invalid + max_len (vectorized) ----------------
__global__ __launch_bounds__(256) void finalize_k(const int* __restrict__ idx,
                                                  const int* __restrict__ lens,
                                                  float* __restrict__ senc,
                                                  float* __restrict__ mask,
                                                  float* __restrict__ omax,
                                                  const int* __restrict__ mlin)
{
    int id = blockIdx.x * 256 + threadIdx.x;
    if (id == 0) omax[0] = (float)mlin[0];
    if (id >= BB * LL * 64) return;
    int row = id >> 6, c = id & 63;
    int b = row / LL, tt = row % LL;
    if (c == 0) mask[row] = (idx[row] == 0) ? 1.f : 0.f;
    if (tt >= lens[b]) *(float4*)&senc[(size_t)row * 256 + c * 4] = make_float4(0.f, 0.f, 0.f, 0.f);
}

// ---------------- gated-attention context (bf16 in, bf16 out) ----------------
template<int D>
__global__ __launch_bounds__(256) void attn_ctx_k(const unsigned short* __restrict__ hid,
                                                  const int* __restrict__ adj,
                                                  const float* __restrict__ att0,
                                                  const float* __restrict__ att1,
                                                  unsigned short* __restrict__ ctx)
{
    constexpr int V = D / 64;
    int lane = threadIdx.x & 63, wid = threadIdx.x >> 6;
    int n = blockIdx.x * 4 + wid;
    if (n >= NN) return;
    float a0[V], a1[V], sv[V];
#pragma unroll
    for (int j = 0; j < V; ++j) {
        a0[j] = att0[lane * V + j];
        a1[j] = att1[lane * V + j];
    }
    {
        if (V == 2) {
            unsigned int u = *(const unsigned int*)(hid + (size_t)n * D + lane * 2);
            sv[0] = bf2f(u); sv[1] = bf2f(u >> 16);
        } else {
            uint2 u = *(const uint2*)(hid + (size_t)n * D + lane * 4);
            sv[0] = bf2f(u.x); sv[1] = bf2f(u.x >> 16);
            sv[2] = bf2f(u.y); sv[3] = bf2f(u.y >> 16);
        }
    }
    float p = 0.f;
#pragma unroll
    for (int j = 0; j < V; ++j) p += sv[j] * a0[j];
#pragma unroll
    for (int m = 1; m < 64; m <<= 1) p += __shfl_xor(p, m);
    float s_self = p;
    float nv[KNB][V];
    float sc[KNB];
#pragma unroll
    for (int k = 0; k < KNB; ++k) {
        int nb = adj[n * KNB + k];
        float qv = 0.f;
        if (nb < NN) {
            if (V == 2) {
                unsigned int u = *(const unsigned int*)(hid + (size_t)nb * D + lane * 2);
                nv[k][0] = bf2f(u); nv[k][1] = bf2f(u >> 16);
            } else {
                uint2 u = *(const uint2*)(hid + (size_t)nb * D + lane * 4);
                nv[k][0] = bf2f(u.x); nv[k][1] = bf2f(u.x >> 16);
                nv[k][2] = bf2f(u.y); nv[k][3] = bf2f(u.y >> 16);
            }
        } else {
#pragma unroll
            for (int j = 0; j < V; ++j) nv[k][j] = 0.f;
        }
#pragma unroll
        for (int j = 0; j < V; ++j) qv += nv[k][j] * a1[j];
#pragma unroll
        for (int m = 1; m < 64; m <<= 1) qv += __shfl_xor(qv, m);
        sc[k] = s_self + qv;
    }
    float mx = sc[0];
#pragma unroll
    for (int k = 1; k < KNB; ++k) mx = fmaxf(mx, sc[k]);
    float s = 0.f;
#pragma unroll
    for (int k = 0; k < KNB; ++k) { sc[k] = fexp2((sc[k] - mx) * 1.4426950408889634f); s += sc[k]; }
    float inv = frcp(s);
#pragma unroll
    for (int j2 = 0; j2 < V; j2 += 2) {
        float c0 = 0.f, c1 = 0.f;
#pragma unroll
        for (int k = 0; k < KNB; ++k) { c0 += sc[k] * nv[k][j2]; c1 += sc[k] * nv[k][j2 + 1]; }
        unsigned int pk = (unsigned int)f2bf(c0 * inv) | ((unsigned int)f2bf(c1 * inv) << 16);
        *(unsigned int*)(ctx + (size_t)n * D + lane * V + j2) = pk;
    }
}

// ---------------- graph max pool: two-stage ----------------
__global__ __launch_bounds__(512) void gmax1_k(const float* __restrict__ gh, float* __restrict__ part)
{
    int g = blockIdx.x, ch = blockIdx.y;
    int c = threadIdx.x;
    const float* p = gh + ((size_t)g * 1000 + ch * (1000 / GCH)) * 512 + c;
    float m = -1e30f;
#pragma unroll 5
    for (int i = 0; i < 1000 / GCH; ++i) m = fmaxf(m, p[(size_t)i * 512]);
    part[((size_t)g * GCH + ch) * 512 + c] = m;
}

__global__ __launch_bounds__(512) void gmax2_k(const float* __restrict__ part, float* __restrict__ ge)
{
    int g = blockIdx.x;
    int c = threadIdx.x;
    float m = -1e30f;
#pragma unroll
    for (int i = 0; i < GCH; ++i) m = fmaxf(m, part[((size_t)g * GCH + i) * 512 + c]);
    ge[g * 512 + c] = m;
}

extern "C" void kernel_launch(void* const* d_in, const int* in_sizes, int n_in,
                              void* d_out, int out_size, void* d_ws, size_t ws_size,
                              hipStream_t stream)
{
    const float* embed = (const float*)d_in[0];
    const float* sfWhh = (const float*)d_in[2];
    const float* sfb   = (const float*)d_in[3];
    const float* sbWhh = (const float*)d_in[5];
    const float* sbb   = (const float*)d_in[6];
    const float* ndWih = (const float*)d_in[7];
    const float* ndWhh = (const float*)d_in[8];
    const float* ndb   = (const float*)d_in[9];
    const int* nodefeat = (const int*)d_in[30];
    const int* adjs[2]  = {(const int*)d_in[31], (const int*)d_in[32]};
    const int* idxseq   = (const int*)d_in[33];
    const int* lens     = (const int*)d_in[34];
    const int* mlin     = (const int*)d_in[35];

    // ---- workspace layout (f32 units), phase-aliased ----
    float* ws   = (float*)d_ws;
    float* wt   = ws;                         // 131,072 : 2 seq Whh transposed (permuted cols)
    float* P1   = ws + 262144;
    float* xgf  = P1;                         // 3,276,800
    float* xgb  = P1 + 3276800;               // 3,276,800
    int*   tokrev = (int*)(P1 + 6553600);     // 6,400 ints
    float* cn   = P1;                         // phase 2 cell state (3,200,000 f32)
    unsigned short* HA = (unsigned short*)P1;               // phase 3 (6.4M us)
    unsigned short* HB = (unsigned short*)(P1 + 3200000);   // (6.4M us)
    unsigned short* embedbf = (unsigned short*)(ws + 6822144);   // 4,096,000 us
    unsigned short* warena  = (unsigned short*)(ws + 8870144);   // 884,736 us
    unsigned short* hbf     = (unsigned short*)(ws + 9312512);   // 3,200,000 us
    unsigned short* hbf2    = (unsigned short*)(ws + 10912512);  // 3,200,000 us
    unsigned short* ctxb    = (unsigned short*)(ws + 12512512);  // 6,400,000 us
    unsigned short* gctxb   = (unsigned short*)(ws + 15712512);  // 6,400,000 us
    float* gmaxp = ws + 10912512;             // phase 4 partials (256,000 f32), hbf2 dead

    float* outf  = (float*)d_out;
    float* gh    = outf;                 // 12,800,000
    float* ge    = outf + 12800000;      // 12,800
    float* omax  = outf + 12812800;      // 1
    float* senc  = outf + 12812801;      // 1,638,400
    float* omask = outf + 14451201;      // 6,400

    // phase 0: preps
    transpose2_k<<<dim3(512), dim3(256), 0, stream>>>(sfWhh, sbWhh, wt);
    tokrev_k<<<dim3((BB * LL + 255) / 256), dim3(256), 0, stream>>>(idxseq, lens, tokrev);
    embconv_k<<<dim3(VV * 128 / 256), dim3(256), 0, stream>>>(embed, embedbf);
    wprep_k<<<dim3(3456), dim3(256), 0, stream>>>(ndWih, ndWhh,
        (const float*)d_in[12], (const float*)d_in[14], (const float*)d_in[16], (const float*)d_in[18],
        (const float*)d_in[22], (const float*)d_in[24], (const float*)d_in[26], (const float*)d_in[28],
        (const float*)d_in[1], (const float*)d_in[4], warena);

    // phase 1: sequence bi-LSTM (xg via bf16 MFMA with gate-interleaved output cols)
    hgemm_k<1, 0, 1, 1><<<dim3(50, 4), dim3(256), 0, stream>>>(embedbf, 0, idxseq, 1, 0, nullptr,
        warena + 753664, sfb, nullptr, 0, xgf, 512, 0, BB * LL, 512, 128, nullptr);
    hgemm_k<1, 0, 1, 1><<<dim3(50, 4), dim3(256), 0, stream>>>(embedbf, 0, tokrev, 1, 0, nullptr,
        warena + 819200, sbb, nullptr, 0, xgb, 512, 0, BB * LL, 512, 128, nullptr);
    seq_lstm_k<<<dim3(2 * BB), dim3(512), 0, stream>>>(xgf, xgb, wt, lens, senc);
    finalize_k<<<dim3(1600), dim3(256), 0, stream>>>(idxseq, lens, senc, omask, omax, mlin);

    // phase 2: node LSTM (4 steps), cell fused into GEMM epilogue, h double-buffered
    zero_k<<<dim3((3200000 + 255) / 256), dim3(256), 0, stream>>>(cn, 3200000);
    zero_k<<<dim3((1600000 + 255) / 256), dim3(256), 0, stream>>>((float*)hbf, 1600000);
    for (int t = 0; t < NTK; ++t) {
        const unsigned short* hrd = (t & 1) ? hbf2 : hbf;
        unsigned short* hwr = (t & 1) ? hbf : hbf2;   // t=3 writes hbf (final)
        hgemm_k<2, 3, 0, 0><<<dim3(196, 4), dim3(256), 0, stream>>>(embedbf, 0, nodefeat, NTK, t, hrd,
            warena, ndb, nullptr, 0, hwr, 128, 0, NN, 512, 256, cn);
    }

    // phase 3: graph attention layers
    for (int dir = 0; dir < 2; ++dir) {
        int base = 10 + dir * 10;
        const float* att0w = (const float*)d_in[base + 0];
        const float* attrw = (const float*)d_in[base + 1];
        const float* bg0   = (const float*)d_in[base + 3];
        const float* bgr   = (const float*)d_in[base + 5];
        const float* bo0   = (const float*)d_in[base + 7];
        const float* bor   = (const float*)d_in[base + 9];
        const int* adj = adjs[dir];
        const unsigned short* wb = warena + 131072 + dir * 311296;
        for (int l = 0; l < 3; ++l) {
            int D = (l == 0) ? 128 : 256;
            int j = l - 1;
            const unsigned short* cur = (l == 0) ? hbf : (l == 1 ? HA : HB);
            const float* a0 = (l == 0) ? att0w : attrw + (size_t)j * 512;
            const float* a1 = (l == 0) ? att0w + 128 : attrw + (size_t)j * 512 + 256;
            const unsigned short* wg  = (l == 0) ? wb : wb + 16384 + j * 65536;
            const unsigned short* wos = (l == 0) ? wb + 147456 : wb + 180224 + (j * 2 + 0) * 32768;
            const unsigned short* won = (l == 0) ? wb + 163840 : wb + 180224 + (j * 2 + 1) * 32768;
            const float* bg = (l == 0) ? bg0 : bgr + (size_t)j * 256;
            const float* bos = (l == 0) ? bo0 : bor + (size_t)j * 256;
            const float* bon = (l == 0) ? bo0 + 128 : bor + (size_t)j * 256 + 128;

            if (D == 128)
                attn_ctx_k<128><<<dim3(NN / 4), dim3(256), 0, stream>>>(cur, adj, a0, a1, ctxb);
            else
                attn_ctx_k<256><<<dim3(NN / 4), dim3(256), 0, stream>>>(cur, adj, a0, a1, ctxb);

            hgemm_k<0, 2, 0, 0><<<dim3(196, D / 128), dim3(256), 0, stream>>>(cur, D, nullptr, 0, 0, nullptr,
                wg, bg, ctxb, D, gctxb, D, 0, NN, D, D, nullptr);

            if (l == 2) {
                hgemm_k<0, 1, 1, 0><<<dim3(196, 1), dim3(256), 0, stream>>>(cur, D, nullptr, 0, 0, nullptr,
                    wos, bos, nullptr, 0, gh, 512, dir * 256, NN, 128, D, nullptr);
                hgemm_k<0, 1, 1, 0><<<dim3(196, 1), dim3(256), 0, stream>>>(gctxb, D, nullptr, 0, 0, nullptr,
                    won, bon, nullptr, 0, gh, 512, dir * 256 + 128, NN, 128, D, nullptr);
            } else {
                unsigned short* ob = (l == 0) ? HA : HB;
                hgemm_k<0, 1, 0, 0><<<dim3(196, 1), dim3(256), 0, stream>>>(cur, D, nullptr, 0, 0, nullptr,
                    wos, bos, nullptr, 0, ob, 256, 0, NN, 128, D, nullptr);
                hgemm_k<0, 1, 0, 0><<<dim3(196, 1), dim3(256), 0, stream>>>(gctxb, D, nullptr, 0, 0, nullptr,
                    won, bon, nullptr, 0, ob, 256, 128, NN, 128, D, nullptr);
            }
        }
    }

    // phase 4: graph embedding max-pool (two-stage)
    gmax1_k<<<dim3(NGRAPH, GCH), dim3(512), 0, stream>>>(gh, gmaxp);
    gmax2_k<<<dim3(NGRAPH), dim3(512), 0, stream>>>(gmaxp, ge);
}

// Round 5
// 1133.204 us; speedup vs baseline: 1.8138x; 1.0341x over previous
//
#include <hip/hip_runtime.h>
#include <math.h>

#define NN 25000
#define KNB 16
#define HH 128
#define VV 32000
#define BB 50
#define LL 128
#define NTK 4
#define NGRAPH 25
#define GCH 20

typedef __attribute__((ext_vector_type(8))) short s16x8;
typedef __attribute__((ext_vector_type(4))) float f32x4;
typedef _Float16 h16x2 __attribute__((ext_vector_type(2)));

__device__ __forceinline__ float fexp2(float x) {
#if __has_builtin(__builtin_amdgcn_exp2f)
    return __builtin_amdgcn_exp2f(x);
#else
    return exp2f(x);
#endif
}
__device__ __forceinline__ float frcp(float x) {
#if __has_builtin(__builtin_amdgcn_rcpf)
    return __builtin_amdgcn_rcpf(x);
#else
    return 1.f / x;
#endif
}
__device__ __forceinline__ float fsigm(float x) { return frcp(1.f + fexp2(x * -1.4426950408889634f)); }
__device__ __forceinline__ float ftanh(float x) { return 1.f - 2.f * frcp(1.f + fexp2(x * 2.8853900817779268f)); }

__device__ __forceinline__ unsigned short f2bf(float x) {
    unsigned int u = __float_as_uint(x);
    unsigned int r = (u + 0x7fffu + ((u >> 16) & 1u)) >> 16;
    return (unsigned short)r;
}
__device__ __forceinline__ float bf2f(unsigned int b) {
    return __uint_as_float((b & 0xffffu) << 16);
}

// packed f16 dot2: acc += a.lo*b.lo + a.hi*b.hi
__device__ __forceinline__ float hdot(unsigned int a, unsigned int b, float c) {
#if __has_builtin(__builtin_amdgcn_fdot2)
    return __builtin_amdgcn_fdot2(__builtin_bit_cast(h16x2, a), __builtin_bit_cast(h16x2, b), c, false);
#else
    h16x2 av = __builtin_bit_cast(h16x2, a), bv = __builtin_bit_cast(h16x2, b);
    return c + (float)av[0] * (float)bv[0] + (float)av[1] * (float)bv[1];
#endif
}

__global__ __launch_bounds__(256) void zero_k(float* __restrict__ p, int n)
{
    int i = blockIdx.x * 256 + threadIdx.x;
    if (i < n) p[i] = 0.f;
}

// ---------------- embed f32 -> bf16 ----------------
__global__ __launch_bounds__(256) void embconv_k(const float* __restrict__ e,
                                                 unsigned short* __restrict__ o)
{
    int i = blockIdx.x * 256 + threadIdx.x;
    if (i < VV * 128) o[i] = f2bf(e[i]);
}

// ---------------- weight prep: convert+transpose weights ----------------
// arena layout (ushort elems):
//   nodeWt [512][256] @ 0, row r = unit*4+gate (gate-interleaved), cols = [Wih | Whh]
//   per dir wb = 131072 + dir*311296:
//     wg0t  [128][128] @ wb+0
//     wgrt  [256][256] @ wb+16384 + j*65536   (j=0,1)
//     wo0st [128][128] @ wb+147456 ; wo0nt @ wb+163840
//     wort  [128][256] @ wb+180224 + (j*2+s)*32768
//   sfWih bf16 [512][128] @ 753664 ; sbWih @ 819200
//   seq Whh f16 packed @ 884736: per dir 131072 us; u32 idx = k2*512 + n  (n gate-interleaved)
//   total 1146880
__global__ __launch_bounds__(256) void wprep_k(
    const float* __restrict__ ndWih, const float* __restrict__ ndWhh,
    const float* __restrict__ fWg0, const float* __restrict__ fWgr,
    const float* __restrict__ fWo0, const float* __restrict__ fWor,
    const float* __restrict__ bWg0, const float* __restrict__ bWgr,
    const float* __restrict__ bWo0, const float* __restrict__ bWor,
    const float* __restrict__ sfWih, const float* __restrict__ sbWih,
    const float* __restrict__ sfWhh, const float* __restrict__ sbWhh,
    unsigned short* __restrict__ dst)
{
    int idx = blockIdx.x * 256 + threadIdx.x;
    if (idx >= 1146880) return;
    if (idx >= 884736) {
        // seq Whh as packed f16, column n = unit*4+gate, pair index k2
        int r = idx - 884736;
        int d = r >> 17;
        int o = r & 131071;
        int pairIdx = o >> 1, hf = o & 1;
        int k2 = pairIdx >> 9, n = pairIdx & 511;
        int k = k2 * 2 + hf;
        int unit = n >> 2, gate = n & 3;
        const float* W = d ? sbWhh : sfWhh;
        _Float16 hv = (_Float16)W[(gate * 128 + unit) * 128 + k];
        dst[idx] = __builtin_bit_cast(unsigned short, hv);
        return;
    }
    float val;
    if (idx < 131072) {
        int r = idx >> 8, k = idx & 255;
        int unit = r >> 2, gate = r & 3;
        int srow = (gate << 7) + unit;
        val = (k < 128) ? ndWih[srow * 128 + k] : ndWhh[srow * 128 + (k - 128)];
    } else if (idx < 753664) {
        int r = idx - 131072;
        int dir = r / 311296;
        int o = r % 311296;
        const float* Wg0 = dir ? bWg0 : fWg0;
        const float* Wgr = dir ? bWgr : fWgr;
        const float* Wo0 = dir ? bWo0 : fWo0;
        const float* Wor = dir ? bWor : fWor;
        if (o < 16384) {
            int n = o >> 7, k = o & 127;
            val = Wg0[k * 128 + n];
        } else if (o < 147456) {
            int p = o - 16384;
            int j = p >> 16, q = p & 65535;
            int n = q >> 8, k = q & 255;
            val = Wgr[j * 65536 + k * 256 + n];
        } else if (o < 180224) {
            int p = o - 147456;
            int s = p >> 14, q = p & 16383;
            int n = q >> 7, k = q & 127;
            val = Wo0[s * 16384 + k * 128 + n];
        } else {
            int p = o - 180224;
            int js = p >> 15, q = p & 32767;
            int n = q >> 8, k = q & 255;
            val = Wor[js * 32768 + k * 128 + n];
        }
    } else if (idx < 819200) {
        val = sfWih[idx - 753664];
    } else {
        val = sbWih[idx - 819200];
    }
    dst[idx] = f2bf(val);
}

__global__ __launch_bounds__(256) void tokrev_k(const int* __restrict__ idx,
                                                const int* __restrict__ lens,
                                                int* __restrict__ tokrev)
{
    int t = blockIdx.x * 256 + threadIdx.x;
    if (t >= BB * LL) return;
    int b = t / LL, tt = t % LL;
    int r = lens[b] - 1 - tt;
    r = r < 0 ? 0 : (r > LL - 1 ? LL - 1 : r);
    tokrev[t] = idx[b * LL + r];
}

// ---------------- bf16 MFMA GEMM ----------------
// AMODE 0: A[m*lda+k]; 1: embed_bf[gidx[m*gs+go]*128+k]; 2: k<128 embed else H2[m*128+k-128]
// EP 0: none; 1: relu; 2: sigmoid(v)*aux_bf16[m*ldaux+n]; 3: fused LSTM cell (gate-interleaved N)
// OF32 1: out f32, 0: out bf16 ; PERM 1: permute out col n -> unit*4+gate (f32 path)
template<int AMODE, int EP, int OF32, int PERM>
__global__ __launch_bounds__(256) void hgemm_k(
    const unsigned short* __restrict__ A, int lda,
    const int* __restrict__ gidx, int gstride, int goff,
    const unsigned short* __restrict__ H2,
    const unsigned short* __restrict__ Wt,   // [N][K] bf16
    const float* __restrict__ bias,
    const unsigned short* __restrict__ aux, int ldaux,
    void* __restrict__ outp, int ldo, int ocol,
    int M, int N, int K, float* __restrict__ cbuf)
{
    __shared__ unsigned short Asm[128 * 64];
    __shared__ unsigned short Bsm[128 * 64];
    const int tid = threadIdx.x;
    const int lane = tid & 63, w = tid >> 6;
    const int wm = w >> 1, wn = w & 1;
    const int bm0 = blockIdx.x * 128, bn0 = blockIdx.y * 128;
    f32x4 acc[4][4];
#pragma unroll
    for (int i = 0; i < 4; ++i)
#pragma unroll
        for (int j = 0; j < 4; ++j) acc[i][j] = (f32x4){0.f, 0.f, 0.f, 0.f};

    for (int kt = 0; kt < K; kt += 64) {
#pragma unroll
        for (int r = 0; r < 4; ++r) {
            int id = tid + r * 256;
            int row = id >> 3, cc = id & 7;
            int m = bm0 + row;
            s16x8 v = {0, 0, 0, 0, 0, 0, 0, 0};
            if (m < M) {
                const unsigned short* src;
                if (AMODE == 0) {
                    src = A + (size_t)m * lda + kt + cc * 8;
                } else if (AMODE == 1) {
                    int g = gidx[m * gstride + goff];
                    src = A + (size_t)g * 128 + kt + cc * 8;
                } else {
                    int k0 = kt + cc * 8;
                    if (k0 < 128) {
                        int g = gidx[m * gstride + goff];
                        src = A + (size_t)g * 128 + k0;
                    } else {
                        src = H2 + (size_t)m * 128 + (k0 - 128);
                    }
                }
                v = *(const s16x8*)src;
            }
            int byt = (cc * 16) ^ ((row & 7) << 4);
            *(s16x8*)((char*)Asm + row * 128 + byt) = v;
        }
#pragma unroll
        for (int r = 0; r < 4; ++r) {
            int id = tid + r * 256;
            int row = id >> 3, cc = id & 7;
            s16x8 v = *(const s16x8*)(Wt + (size_t)(bn0 + row) * K + kt + cc * 8);
            int byt = (cc * 16) ^ ((row & 7) << 4);
            *(s16x8*)((char*)Bsm + row * 128 + byt) = v;
        }
        __syncthreads();
#pragma unroll
        for (int ks = 0; ks < 2; ++ks) {
            s16x8 af[4], bf[4];
#pragma unroll
            for (int mi = 0; mi < 4; ++mi) {
                int row = wm * 64 + mi * 16 + (lane & 15);
                int byt = (ks * 64 + ((lane >> 4) * 16)) ^ ((row & 7) << 4);
                af[mi] = *(const s16x8*)((char*)Asm + row * 128 + byt);
            }
#pragma unroll
            for (int ni = 0; ni < 4; ++ni) {
                int row = wn * 64 + ni * 16 + (lane & 15);
                int byt = (ks * 64 + ((lane >> 4) * 16)) ^ ((row & 7) << 4);
                bf[ni] = *(const s16x8*)((char*)Bsm + row * 128 + byt);
            }
#pragma unroll
            for (int mi = 0; mi < 4; ++mi)
#pragma unroll
                for (int ni = 0; ni < 4; ++ni)
                    acc[mi][ni] = __builtin_amdgcn_mfma_f32_16x16x32_bf16(af[mi], bf[ni], acc[mi][ni], 0, 0, 0);
        }
        __syncthreads();
    }
    if (EP == 3) {
#pragma unroll
        for (int mi = 0; mi < 4; ++mi) {
#pragma unroll
            for (int ni = 0; ni < 4; ++ni) {
                int n = bn0 + wn * 64 + ni * 16 + (lane & 15);
                int unit = n >> 2, gate = n & 3;
                float bval = bias[(gate << 7) + unit];
#pragma unroll
                for (int j = 0; j < 4; ++j) {
                    int m = bm0 + wm * 64 + mi * 16 + (lane >> 4) * 4 + j;
                    float v = acc[mi][ni][j] + bval;
                    float tv = (gate == 2) ? ftanh(v) : fsigm(v);
                    float v1 = __shfl_xor(tv, 1), v2 = __shfl_xor(tv, 2), v3 = __shfl_xor(tv, 3);
                    if (gate == 0 && m < M) {
                        float cc = cbuf[(size_t)m * HH + unit];
                        cc = v1 * cc + tv * v2;
                        cbuf[(size_t)m * HH + unit] = cc;
                        ((unsigned short*)outp)[(size_t)m * HH + unit] = f2bf(v3 * ftanh(cc));
                    }
                }
            }
        }
    } else {
#pragma unroll
        for (int mi = 0; mi < 4; ++mi) {
#pragma unroll
            for (int ni = 0; ni < 4; ++ni) {
                int n = bn0 + wn * 64 + ni * 16 + (lane & 15);
#pragma unroll
                for (int j = 0; j < 4; ++j) {
                    int m = bm0 + wm * 64 + mi * 16 + (lane >> 4) * 4 + j;
                    if (m < M) {
                        float v = acc[mi][ni][j] + bias[n];
                        if (EP == 1) v = fmaxf(v, 0.f);
                        if (EP == 2) v = fsigm(v) * bf2f(aux[(size_t)m * ldaux + n]);
                        int nn = PERM ? (((n & 127) << 2) | (n >> 7)) : n;
                        if (OF32) ((float*)outp)[(size_t)m * ldo + ocol + nn] = v;
                        else ((unsigned short*)outp)[(size_t)m * ldo + ocol + nn] = f2bf(v);
                    }
                }
            }
        }
    }
}

// ---------------- per-sequence LSTM recurrence (packed f16 dot2, gate-interleaved) ----------------
__global__ __launch_bounds__(512, 2) void seq_lstm_k(const float* __restrict__ xgf,
                                                     const float* __restrict__ xgb,
                                                     const unsigned short* __restrict__ wseq,
                                                     const int* __restrict__ lens,
                                                     float* __restrict__ senc)
{
    int bid = blockIdx.x;
    int dir = bid >= BB ? 1 : 0;
    int b = dir ? bid - BB : bid;
    int len = lens[b];
    const float* xg = (dir ? xgb : xgf) + (size_t)b * LL * 512;
    const unsigned int* wp = (const unsigned int*)(wseq + dir * 131072);
    int tid = threadIdx.x;
    int q = tid & 3, unit = tid >> 2;
    unsigned int wreg[64];   // 64 packed f16 pairs = this thread's Whh column
#pragma unroll
    for (int k2 = 0; k2 < 64; ++k2) wreg[k2] = wp[k2 * 512 + tid];
    __shared__ __align__(16) unsigned short hls[2][128];   // f16 h double-buffer
    float cj = 0.f;
    if (tid < 128) hls[0][tid] = 0;
    __syncthreads();
    float xcur = xg[tid];
    int pb = 0;
    for (int t = 0; t < len; ++t) {
        float xnext = (t + 1 < len) ? xg[(size_t)(t + 1) * 512 + tid] : 0.f;
        const uint4* hp = (const uint4*)&hls[pb][0];   // 16 x uint4 = 128 f16
        float p0 = 0.f, p1 = 0.f, p2 = 0.f, p3 = 0.f;
#pragma unroll
        for (int i = 0; i < 4; ++i) {
            uint4 h0 = hp[i * 4 + 0], h1 = hp[i * 4 + 1], h2 = hp[i * 4 + 2], h3 = hp[i * 4 + 3];
            const unsigned int* w0 = &wreg[i * 16];
            p0 = hdot(h0.x, w0[0], p0);  p0 = hdot(h0.y, w0[1], p0);
            p0 = hdot(h0.z, w0[2], p0);  p0 = hdot(h0.w, w0[3], p0);
            p1 = hdot(h1.x, w0[4], p1);  p1 = hdot(h1.y, w0[5], p1);
            p1 = hdot(h1.z, w0[6], p1);  p1 = hdot(h1.w, w0[7], p1);
            p2 = hdot(h2.x, w0[8], p2);  p2 = hdot(h2.y, w0[9], p2);
            p2 = hdot(h2.z, w0[10], p2); p2 = hdot(h2.w, w0[11], p2);
            p3 = hdot(h3.x, w0[12], p3); p3 = hdot(h3.y, w0[13], p3);
            p3 = hdot(h3.z, w0[14], p3); p3 = hdot(h3.w, w0[15], p3);
        }
        float accv = xcur + ((p0 + p1) + (p2 + p3));
        float tv = (q == 2) ? ftanh(accv) : fsigm(accv);
        float v1 = __shfl_xor(tv, 1), v2 = __shfl_xor(tv, 2), v3 = __shfl_xor(tv, 3);
        if (q == 0) {
            cj = v1 * cj + tv * v2;           // f*c + i*g
            float hv = v3 * ftanh(cj);        // o*tanh(c)
            _Float16 hh = (_Float16)hv;
            hls[pb ^ 1][unit] = __builtin_bit_cast(unsigned short, hh);
            int tout = dir ? (len - 1 - t) : t;
            senc[((size_t)b * LL + tout) * 256 + dir * 128 + unit] = hv;
        }
        __syncthreads();
        pb ^= 1;
        xcur = xnext;
    }
}

// ---------------- mask + zero-invalid + max_len (vectorized) ----------------
__global__ __launch_bounds__(256) void finalize_k(const int* __restrict__ idx,
                                                  const int* __restrict__ lens,
                                                  float* __restrict__ senc,
                                                  float* __restrict__ mask,
                                                  float* __restrict__ omax,
                                                  const int* __restrict__ mlin)
{
    int id = blockIdx.x * 256 + threadIdx.x;
    if (id == 0) omax[0] = (float)mlin[0];
    if (id >= BB * LL * 64) return;
    int row = id >> 6, c = id & 63;
    int b = row / LL, tt = row % LL;
    if (c == 0) mask[row] = (idx[row] == 0) ? 1.f : 0.f;
    if (tt >= lens[b]) *(float4*)&senc[(size_t)row * 256 + c * 4] = make_float4(0.f, 0.f, 0.f, 0.f);
}

// ---------------- gated-attention context (bf16 in, bf16 out) ----------------
template<int D>
__global__ __launch_bounds__(256) void attn_ctx_k(const unsigned short* __restrict__ hid,
                                                  const int* __restrict__ adj,
                                                  const float* __restrict__ att0,
                                                  const float* __restrict__ att1,
                                                  unsigned short* __restrict__ ctx)
{
    constexpr int V = D / 64;
    int lane = threadIdx.x & 63, wid = threadIdx.x >> 6;
    int n = blockIdx.x * 4 + wid;
    if (n >= NN) return;
    float a0[V], a1[V], sv[V];
#pragma unroll
    for (int j = 0; j < V; ++j) {
        a0[j] = att0[lane * V + j];
        a1[j] = att1[lane * V + j];
    }
    {
        if (V == 2) {
            unsigned int u = *(const unsigned int*)(hid + (size_t)n * D + lane * 2);
            sv[0] = bf2f(u); sv[1] = bf2f(u >> 16);
        } else {
            uint2 u = *(const uint2*)(hid + (size_t)n * D + lane * 4);
            sv[0] = bf2f(u.x); sv[1] = bf2f(u.x >> 16);
            sv[2] = bf2f(u.y); sv[3] = bf2f(u.y >> 16);
        }
    }
    float p = 0.f;
#pragma unroll
    for (int j = 0; j < V; ++j) p += sv[j] * a0[j];
#pragma unroll
    for (int m = 1; m < 64; m <<= 1) p += __shfl_xor(p, m);
    float s_self = p;
    float nv[KNB][V];
    float sc[KNB];
#pragma unroll
    for (int k = 0; k < KNB; ++k) {
        int nb = adj[n * KNB + k];
        float qv = 0.f;
        if (nb < NN) {
            if (V == 2) {
                unsigned int u = *(const unsigned int*)(hid + (size_t)nb * D + lane * 2);
                nv[k][0] = bf2f(u); nv[k][1] = bf2f(u >> 16);
            } else {
                uint2 u = *(const uint2*)(hid + (size_t)nb * D + lane * 4);
                nv[k][0] = bf2f(u.x); nv[k][1] = bf2f(u.x >> 16);
                nv[k][2] = bf2f(u.y); nv[k][3] = bf2f(u.y >> 16);
            }
        } else {
#pragma unroll
            for (int j = 0; j < V; ++j) nv[k][j] = 0.f;
        }
#pragma unroll
        for (int j = 0; j < V; ++j) qv += nv[k][j] * a1[j];
#pragma unroll
        for (int m = 1; m < 64; m <<= 1) qv += __shfl_xor(qv, m);
        sc[k] = s_self + qv;
    }
    float mx = sc[0];
#pragma unroll
    for (int k = 1; k < KNB; ++k) mx = fmaxf(mx, sc[k]);
    float s = 0.f;
#pragma unroll
    for (int k = 0; k < KNB; ++k) { sc[k] = fexp2((sc[k] - mx) * 1.4426950408889634f); s += sc[k]; }
    float inv = frcp(s);
#pragma unroll
    for (int j2 = 0; j2 < V; j2 += 2) {
        float c0 = 0.f, c1 = 0.f;
#pragma unroll
        for (int k = 0; k < KNB; ++k) { c0 += sc[k] * nv[k][j2]; c1 += sc[k] * nv[k][j2 + 1]; }
        unsigned int pk = (unsigned int)f2bf(c0 * inv) | ((unsigned int)f2bf(c1 * inv) << 16);
        *(unsigned int*)(ctx + (size_t)n * D + lane * V + j2) = pk;
    }
}

// ---------------- graph max pool: two-stage ----------------
__global__ __launch_bounds__(512) void gmax1_k(const float* __restrict__ gh, float* __restrict__ part)
{
    int g = blockIdx.x, ch = blockIdx.y;
    int c = threadIdx.x;
    const float* p = gh + ((size_t)g * 1000 + ch * (1000 / GCH)) * 512 + c;
    float m = -1e30f;
#pragma unroll 5
    for (int i = 0; i < 1000 / GCH; ++i) m = fmaxf(m, p[(size_t)i * 512]);
    part[((size_t)g * GCH + ch) * 512 + c] = m;
}

__global__ __launch_bounds__(512) void gmax2_k(const float* __restrict__ part, float* __restrict__ ge)
{
    int g = blockIdx.x;
    int c = threadIdx.x;
    float m = -1e30f;
#pragma unroll
    for (int i = 0; i < GCH; ++i) m = fmaxf(m, part[((size_t)g * GCH + i) * 512 + c]);
    ge[g * 512 + c] = m;
}

extern "C" void kernel_launch(void* const* d_in, const int* in_sizes, int n_in,
                              void* d_out, int out_size, void* d_ws, size_t ws_size,
                              hipStream_t stream)
{
    const float* embed = (const float*)d_in[0];
    const float* sfWhh = (const float*)d_in[2];
    const float* sfb   = (const float*)d_in[3];
    const float* sbWhh = (const float*)d_in[5];
    const float* sbb   = (const float*)d_in[6];
    const float* ndWih = (const float*)d_in[7];
    const float* ndWhh = (const float*)d_in[8];
    const float* ndb   = (const float*)d_in[9];
    const int* nodefeat = (const int*)d_in[30];
    const int* adjs[2]  = {(const int*)d_in[31], (const int*)d_in[32]};
    const int* idxseq   = (const int*)d_in[33];
    const int* lens     = (const int*)d_in[34];
    const int* mlin     = (const int*)d_in[35];

    // ---- workspace layout (f32 units), phase-aliased ----
    float* ws   = (float*)d_ws;
    float* P1   = ws + 262144;
    float* xgf  = P1;                         // 3,276,800
    float* xgb  = P1 + 3276800;               // 3,276,800
    int*   tokrev = (int*)(P1 + 6553600);     // 6,400 ints
    float* cn   = P1;                         // phase 2 cell state (3,200,000 f32)
    unsigned short* HA = (unsigned short*)P1;               // phase 3 (6.4M us)
    unsigned short* HB = (unsigned short*)(P1 + 3200000);   // (6.4M us)
    unsigned short* embedbf = (unsigned short*)(ws + 6822144);   // 4,096,000 us
    unsigned short* warena  = (unsigned short*)(ws + 8870144);   // 1,146,880 us
    unsigned short* hbf     = (unsigned short*)(ws + 9443584);   // 3,200,000 us
    unsigned short* hbf2    = (unsigned short*)(ws + 11043584);  // 3,200,000 us
    unsigned short* ctxb    = (unsigned short*)(ws + 12643584);  // 6,400,000 us
    unsigned short* gctxb   = (unsigned short*)(ws + 15843584);  // 6,400,000 us
    float* gmaxp = ws + 11043584;             // phase 4 partials (256,000 f32), hbf2 dead

    float* outf  = (float*)d_out;
    float* gh    = outf;                 // 12,800,000
    float* ge    = outf + 12800000;      // 12,800
    float* omax  = outf + 12812800;      // 1
    float* senc  = outf + 12812801;      // 1,638,400
    float* omask = outf + 14451201;      // 6,400

    // phase 0: preps
    tokrev_k<<<dim3((BB * LL + 255) / 256), dim3(256), 0, stream>>>(idxseq, lens, tokrev);
    embconv_k<<<dim3(VV * 128 / 256), dim3(256), 0, stream>>>(embed, embedbf);
    wprep_k<<<dim3(4480), dim3(256), 0, stream>>>(ndWih, ndWhh,
        (const float*)d_in[12], (const float*)d_in[14], (const float*)d_in[16], (const float*)d_in[18],
        (const float*)d_in[22], (const float*)d_in[24], (const float*)d_in[26], (const float*)d_in[28],
        (const float*)d_in[1], (const float*)d_in[4], sfWhh, sbWhh, warena);

    // phase 1: sequence bi-LSTM (xg via bf16 MFMA with gate-interleaved output cols)
    hgemm_k<1, 0, 1, 1><<<dim3(50, 4), dim3(256), 0, stream>>>(embedbf, 0, idxseq, 1, 0, nullptr,
        warena + 753664, sfb, nullptr, 0, xgf, 512, 0, BB * LL, 512, 128, nullptr);
    hgemm_k<1, 0, 1, 1><<<dim3(50, 4), dim3(256), 0, stream>>>(embedbf, 0, tokrev, 1, 0, nullptr,
        warena + 819200, sbb, nullptr, 0, xgb, 512, 0, BB * LL, 512, 128, nullptr);
    seq_lstm_k<<<dim3(2 * BB), dim3(512), 0, stream>>>(xgf, xgb, warena + 884736, lens, senc);
    finalize_k<<<dim3(1600), dim3(256), 0, stream>>>(idxseq, lens, senc, omask, omax, mlin);

    // phase 2: node LSTM (4 steps), cell fused into GEMM epilogue, h double-buffered
    zero_k<<<dim3((3200000 + 255) / 256), dim3(256), 0, stream>>>(cn, 3200000);
    zero_k<<<dim3((1600000 + 255) / 256), dim3(256), 0, stream>>>((float*)hbf, 1600000);
    for (int t = 0; t < NTK; ++t) {
        const unsigned short* hrd = (t & 1) ? hbf2 : hbf;
        unsigned short* hwr = (t & 1) ? hbf : hbf2;   // t=3 writes hbf (final)
        hgemm_k<2, 3, 0, 0><<<dim3(196, 4), dim3(256), 0, stream>>>(embedbf, 0, nodefeat, NTK, t, hrd,
            warena, ndb, nullptr, 0, hwr, 128, 0, NN, 512, 256, cn);
    }

    // phase 3: graph attention layers
    for (int dir = 0; dir < 2; ++dir) {
        int base = 10 + dir * 10;
        const float* att0w = (const float*)d_in[base + 0];
        const float* attrw = (const float*)d_in[base + 1];
        const float* bg0   = (const float*)d_in[base + 3];
        const float* bgr   = (const float*)d_in[base + 5];
        const float* bo0   = (const float*)d_in[base + 7];
        const float* bor   = (const float*)d_in[base + 9];
        const int* adj = adjs[dir];
        const unsigned short* wb = warena + 131072 + dir * 311296;
        for (int l = 0; l < 3; ++l) {
            int D = (l == 0) ? 128 : 256;
            int j = l - 1;
            const unsigned short* cur = (l == 0) ? hbf : (l == 1 ? HA : HB);
            const float* a0 = (l == 0) ? att0w : attrw + (size_t)j * 512;
            const float* a1 = (l == 0) ? att0w + 128 : attrw + (size_t)j * 512 + 256;
            const unsigned short* wg  = (l == 0) ? wb : wb + 16384 + j * 65536;
            const unsigned short* wos = (l == 0) ? wb + 147456 : wb + 180224 + (j * 2 + 0) * 32768;
            const unsigned short* won = (l == 0) ? wb + 163840 : wb + 180224 + (j * 2 + 1) * 32768;
            const float* bg = (l == 0) ? bg0 : bgr + (size_t)j * 256;
            const float* bos = (l == 0) ? bo0 : bor + (size_t)j * 256;
            const float* bon = (l == 0) ? bo0 + 128 : bor + (size_t)j * 256 + 128;

            if (D == 128)
                attn_ctx_k<128><<<dim3(NN / 4), dim3(256), 0, stream>>>(cur, adj, a0, a1, ctxb);
            else
                attn_ctx_k<256><<<dim3(NN / 4), dim3(256), 0, stream>>>(cur, adj, a0, a1, ctxb);

            hgemm_k<0, 2, 0, 0><<<dim3(196, D / 128), dim3(256), 0, stream>>>(cur, D, nullptr, 0, 0, nullptr,
                wg, bg, ctxb, D, gctxb, D, 0, NN, D, D, nullptr);

            if (l == 2) {
                hgemm_k<0, 1, 1, 0><<<dim3(196, 1), dim3(256), 0, stream>>>(cur, D, nullptr, 0, 0, nullptr,
                    wos, bos, nullptr, 0, gh, 512, dir * 256, NN, 128, D, nullptr);
                hgemm_k<0, 1, 1, 0><<<dim3(196, 1), dim3(256), 0, stream>>>(gctxb, D, nullptr, 0, 0, nullptr,
                    won, bon, nullptr, 0, gh, 512, dir * 256 + 128, NN, 128, D, nullptr);
            } else {
                unsigned short* ob = (l == 0) ? HA : HB;
                hgemm_k<0, 1, 0, 0><<<dim3(196, 1), dim3(256), 0, stream>>>(cur, D, nullptr, 0, 0, nullptr,
                    wos, bos, nullptr, 0, ob, 256, 0, NN, 128, D, nullptr);
                hgemm_k<0, 1, 0, 0><<<dim3(196, 1), dim3(256), 0, stream>>>(gctxb, D, nullptr, 0, 0, nullptr,
                    won, bon, nullptr, 0, ob, 256, 128, NN, 128, D, nullptr);
            }
        }
    }

    // phase 4: graph embedding max-pool (two-stage)
    gmax1_k<<<dim3(NGRAPH, GCH), dim3(512), 0, stream>>>(gh, gmaxp);
    gmax2_k<<<dim3(NGRAPH), dim3(512), 0, stream>>>(gmaxp, ge);
}